// Round 2
// baseline (13379.016 us; speedup 1.0000x reference)
//
#include <hip/hip_runtime.h>
#include <hip/hip_bf16.h>
#include <stdint.h>

// LSTM B=64 S=1024 D=1024 H=1024, gates f,i,o,g all sigmoid.
// Phase 1: xproj = x@W + bW + bU  (bf16 MFMA GEMM, chunked by ws_size)
// Phase 2: persistent recurrent kernel, 64 WGs (one per 16 h-cols).
//   Fence-free coherence: h + flags via agent-scope atomics (sc0 sc1 -> L3),
//   U streamed from warm L2 every step, 8-line arrival counter barrier.

typedef __attribute__((ext_vector_type(8))) short short8;
typedef __attribute__((ext_vector_type(4))) float floatx4;
typedef __attribute__((ext_vector_type(2))) float floatx2;

__device__ __forceinline__ unsigned short f2bf(float x){
  union { float f; unsigned int u; } v; v.f = x;
  unsigned int r = v.u + 0x7fffu + ((v.u >> 16) & 1u);
  return (unsigned short)(r >> 16);
}
__device__ __forceinline__ float bf2f(unsigned short b){
  union { unsigned int u; float f; } v; v.u = ((unsigned int)b) << 16; return v.f;
}
__device__ __forceinline__ float fsigmoid(float x){ return 1.0f / (1.0f + __expf(-x)); }
// overflow-safe tanh: exp->inf gives 1, exp->0 gives -1, never NaN
__device__ __forceinline__ float ftanh(float x){ return 1.0f - 2.0f / (1.0f + __expf(2.0f * x)); }

// ---- transpose [g][d][h] fp32 -> [g][h][d] bf16 (per-gate 1024x1024) ----
__global__ void k_transpose_bf16(const float* __restrict__ src, unsigned short* __restrict__ dst){
  __shared__ float tile[64][65];
  const int g  = blockIdx.z;
  const int d0 = blockIdx.x * 64;
  const int h0 = blockIdx.y * 64;
  const int t  = threadIdx.x;
  const float* s    = src + ((size_t)g << 20);
  unsigned short* o = dst + ((size_t)g << 20);
  #pragma unroll
  for (int i = 0; i < 16; i++){
    int e = i * 256 + t;
    int r = e >> 6, c = e & 63;
    tile[r][c] = s[(size_t)(d0 + r) * 1024 + (h0 + c)];
  }
  __syncthreads();
  #pragma unroll
  for (int i = 0; i < 16; i++){
    int e = i * 256 + t;
    int a = e >> 6, bb = e & 63;
    o[(size_t)(h0 + a) * 1024 + (d0 + bb)] = f2bf(tile[bb][a]);
  }
}

// ---- convert input chunk (B,S,D) fp32 -> Abuf[(sl*64+b)][d] bf16 ----
__global__ void k_convert_x(const float* __restrict__ inp, unsigned short* __restrict__ abuf, int s0){
  int idx = blockIdx.x * 256 + threadIdx.x;   // 4 floats per thread
  int e = idx * 4;
  int r = e >> 10, d = e & 1023;
  int b = r & 63, sl = r >> 6;
  floatx4 v = *(const floatx4*)(inp + ((size_t)(b * 1024 + (s0 + sl)) * 1024 + d));
  unsigned long long pk = (unsigned long long)f2bf(v[0])
                        | ((unsigned long long)f2bf(v[1]) << 16)
                        | ((unsigned long long)f2bf(v[2]) << 32)
                        | ((unsigned long long)f2bf(v[3]) << 48);
  *(unsigned long long*)(abuf + (size_t)r * 1024 + d) = pk;
}

// ---- xproj GEMM: C[M][4096] = A[M][1024] @ Bt^T + (bW+bU), bf16 out ----
__global__ void __launch_bounds__(256) k_gemm_xproj(
    const unsigned short* __restrict__ A,
    const unsigned short* __restrict__ Bt,   // Wt[4096][1024] (N-major)
    const float* __restrict__ bW,
    const float* __restrict__ bU,
    unsigned short* __restrict__ Cc)
{
  __shared__ unsigned short As[2][128][64];
  __shared__ unsigned short Bs[2][128][64];
  const int t = threadIdx.x;
  const int w = t >> 6;
  const int lane = t & 63;
  const int m0 = blockIdx.x * 128;
  const int n0 = blockIdx.y * 128;
  floatx4 acc[4][4];
  #pragma unroll
  for (int i = 0; i < 4; i++)
    #pragma unroll
    for (int j = 0; j < 4; j++)
      acc[i][j] = (floatx4){0.f, 0.f, 0.f, 0.f};

  auto stage = [&](int bufi, int kt){
    #pragma unroll
    for (int i = 0; i < 4; i++){
      int chunk = i * 256 + t;
      int r = chunk >> 3, j = chunk & 7;
      int js = j ^ (r & 7);           // pre-swizzled global source, linear LDS dest
      __builtin_amdgcn_global_load_lds(
        (const __attribute__((address_space(1))) unsigned int*)(A + (size_t)(m0 + r) * 1024 + kt * 64 + js * 8),
        (__attribute__((address_space(3))) unsigned int*)(&As[bufi][0][0] + (i * 256 + w * 64) * 8), 16, 0, 0);
    }
    #pragma unroll
    for (int i = 0; i < 4; i++){
      int chunk = i * 256 + t;
      int r = chunk >> 3, j = chunk & 7;
      int js = j ^ (r & 7);
      __builtin_amdgcn_global_load_lds(
        (const __attribute__((address_space(1))) unsigned int*)(Bt + (size_t)(n0 + r) * 1024 + kt * 64 + js * 8),
        (__attribute__((address_space(3))) unsigned int*)(&Bs[bufi][0][0] + (i * 256 + w * 64) * 8), 16, 0, 0);
    }
  };

  auto compute = [&](int bufi){
    const int mi0 = (w >> 1) * 64;
    const int ni0 = (w & 1) * 64;
    #pragma unroll
    for (int kc = 0; kc < 2; kc++){
      short8 af[4], bfr[4];
      #pragma unroll
      for (int mi = 0; mi < 4; mi++){
        int row = mi0 + mi * 16 + (lane & 15);
        int j = kc * 4 + (lane >> 4);
        af[mi] = *(const short8*)&As[bufi][row][(j ^ (row & 7)) * 8];
      }
      #pragma unroll
      for (int ni = 0; ni < 4; ni++){
        int row = ni0 + ni * 16 + (lane & 15);
        int j = kc * 4 + (lane >> 4);
        bfr[ni] = *(const short8*)&Bs[bufi][row][(j ^ (row & 7)) * 8];
      }
      #pragma unroll
      for (int mi = 0; mi < 4; mi++)
        #pragma unroll
        for (int ni = 0; ni < 4; ni++)
          acc[mi][ni] = __builtin_amdgcn_mfma_f32_16x16x32_bf16(af[mi], bfr[ni], acc[mi][ni], 0, 0, 0);
    }
  };

  stage(0, 0);
  int buf = 0;
  for (int kt = 0; kt < 16; kt++){
    __syncthreads();
    if (kt < 15) stage(buf ^ 1, kt + 1);
    compute(buf);
    buf ^= 1;
  }

  {
    const int mi0 = (w >> 1) * 64;
    const int ni0 = (w & 1) * 64;
    #pragma unroll
    for (int ni = 0; ni < 4; ni++){
      int col = n0 + ni0 + ni * 16 + (lane & 15);    // col = g*1024 + h
      float bias = bW[col] + bU[col];
      #pragma unroll
      for (int mi = 0; mi < 4; mi++){
        int mrow = m0 + mi0 + mi * 16 + (lane >> 4) * 4;
        #pragma unroll
        for (int r = 0; r < 4; r++)
          Cc[(size_t)(mrow + r) * 4096 + col] = f2bf(acc[mi][ni][r] + bias);
      }
    }
  }
}

// ---- persistent recurrent kernel: 64 WGs, WG owns h-cols [wg*16, wg*16+16) ----
// Wave w = K-quarter [w*256, w*256+256). No fences: h via agent atomics (L3),
// U re-streamed from warm L2 each step, 8-line arrival counter barrier.
__global__ void __launch_bounds__(256, 1) k_lstm_rec(
    const unsigned short* __restrict__ xp,   // [SC*64][4096] bf16 (chunk)
    const unsigned short* __restrict__ Ut,   // [4096][1024] bf16
    unsigned short* hb,                      // [2][64][1024] bf16 double buffer
    float* cstate,                           // [64][1024]
    float* __restrict__ out,                 // (B,S,H) fp32
    float* __restrict__ hlast,
    float* __restrict__ clast,
    int* flags,                              // 8 counter lines, stride 32 ints
    int s_base, int SC)
{
  const int t = threadIdx.x;
  const int w = t >> 6;
  const int lane = t & 63;
  const int wg = blockIdx.x;
  const int c0 = wg * 16;
  // per-wave K-partials, rotation layout: word (w*64+lane)*64 + ((idx+2*lane)&63)
  __shared__ float part[4 * 64 * 64];        // 64 KB

  const int b = t >> 2;            // batch owned in epilogue
  const int ci0 = (t & 3) * 4;     // 4 h-cols owned
  floatx4 c;
  if (s_base == 0) c = (floatx4){0.f, 0.f, 0.f, 0.f};
  else             c = *(const floatx4*)&cstate[(size_t)b * 1024 + c0 + ci0];

  int bail = 20000000;             // bounded spin: deadlock -> terminate (wrong), not hang

  for (int sl = 0; sl < SC; sl++){
    const int s = s_base + sl;
    const int p = s & 1;

    // xp prefetch (independent of h) before the spin
    unsigned long long xv[4];
    #pragma unroll
    for (int g = 0; g < 4; g++)
      xv[g] = *(const unsigned long long*)(xp + ((size_t)(sl * 64 + b)) * 4096 + g * 1024 + c0 + ci0);
    __builtin_amdgcn_sched_barrier(0);

    if (sl > 0){
      if (w == 0){
        const int* cp = &flags[(lane & 7) * 32];
        const int target = 8 * s;          // 8 arrivals/line/step
        while (__hip_atomic_load(cp, __ATOMIC_RELAXED, __HIP_MEMORY_SCOPE_AGENT) < target){
          __builtin_amdgcn_s_sleep(1);
          if (--bail < 0) break;
        }
      }
      __syncthreads();                      // B1: arrival known to all waves
    }

    floatx4 acc[4][4];
    #pragma unroll
    for (int i = 0; i < 4; i++)
      #pragma unroll
      for (int j = 0; j < 4; j++)
        acc[i][j] = (floatx4){0.f, 0.f, 0.f, 0.f};

    // A: h_prev[b][k] via agent-scope atomic 8B loads (bypass L1/L2 -> fresh from L3)
    // B: U slice re-read from warm L2 (plain b128)
    const unsigned short* hbp = hb + (size_t)p * 65536;
    #pragma unroll
    for (int kc = 0; kc < 8; kc++){
      short8 af[4];
      #pragma unroll
      for (int mi = 0; mi < 4; mi++){
        const unsigned long long* pq = (const unsigned long long*)
          (hbp + (size_t)(mi * 16 + (lane & 15)) * 1024 + w * 256 + kc * 32 + (lane >> 4) * 8);
        unsigned long long lo = __hip_atomic_load(pq,     __ATOMIC_RELAXED, __HIP_MEMORY_SCOPE_AGENT);
        unsigned long long hi = __hip_atomic_load(pq + 1, __ATOMIC_RELAXED, __HIP_MEMORY_SCOPE_AGENT);
        union { unsigned long long q[2]; short8 v; } u;
        u.q[0] = lo; u.q[1] = hi;
        af[mi] = u.v;
      }
      short8 bfr[4];
      #pragma unroll
      for (int ni = 0; ni < 4; ni++)
        bfr[ni] = *(const short8*)(Ut + (size_t)(ni * 1024 + c0 + (lane & 15)) * 1024
                                      + w * 256 + kc * 32 + (lane >> 4) * 8);
      #pragma unroll
      for (int mi = 0; mi < 4; mi++)
        #pragma unroll
        for (int ni = 0; ni < 4; ni++)
          acc[mi][ni] = __builtin_amdgcn_mfma_f32_16x16x32_bf16(af[mi], bfr[ni], acc[mi][ni], 0, 0, 0);
    }

    // publish K-partials (rotation layout: writes 2-way conflict = free)
    #pragma unroll
    for (int pi = 0; pi < 32; pi++){
      const int idx = pi * 2;                        // (mi*4+ni)*4 + r, r even
      const int mi = idx >> 4, ni = (idx >> 2) & 3, r = idx & 3;
      const int off = (idx + 2 * lane) & 63;
      *(floatx2*)&part[(w * 64 + lane) * 64 + off] = (floatx2){acc[mi][ni][r], acc[mi][ni][r + 1]};
    }
    __syncthreads();                                  // B2: partials visible

    // epilogue: thread owns (b, ci0..ci0+3)
    float hout[4];
    #pragma unroll
    for (int cc = 0; cc < 4; cc++){
      const int ccol = ci0 + cc;
      const int lp = ((b >> 2) & 3) * 16 + ccol;      // source lane in C-fragment
      float gs[4];
      #pragma unroll
      for (int g = 0; g < 4; g++){
        const int idx = ((b >> 4) * 4 + g) * 4 + (b & 3);
        float sum = bf2f((unsigned short)(xv[g] >> (16 * cc)));
        #pragma unroll
        for (int w2 = 0; w2 < 4; w2++)
          sum += part[(w2 * 64 + lp) * 64 + ((idx + 2 * lp) & 63)];
        gs[g] = sum;
      }
      float fv = fsigmoid(gs[0]);
      float iv = fsigmoid(gs[1]);
      float ov = fsigmoid(gs[2]);
      float gv = fsigmoid(gs[3]);     // reference uses sigmoid for g, not tanh
      float cv = fv * c[cc] + iv * gv;
      c[cc] = cv;
      hout[cc] = ov * ftanh(cv);
    }

    // publish h (agent-scope store -> L3, no fence needed)
    unsigned long long hpk = (unsigned long long)f2bf(hout[0])
                           | ((unsigned long long)f2bf(hout[1]) << 16)
                           | ((unsigned long long)f2bf(hout[2]) << 32)
                           | ((unsigned long long)f2bf(hout[3]) << 48);
    __hip_atomic_store((unsigned long long*)(hb + (size_t)(p ^ 1) * 65536 + (size_t)b * 1024 + c0 + ci0),
                       hpk, __ATOMIC_RELAXED, __HIP_MEMORY_SCOPE_AGENT);

    if (s == 1023){
      *(floatx4*)&hlast[(size_t)b * 1024 + c0 + ci0] = (floatx4){hout[0], hout[1], hout[2], hout[3]};
      *(floatx4*)&clast[(size_t)b * 1024 + c0 + ci0] = c;
    }

    asm volatile("s_waitcnt vmcnt(0)" ::: "memory");  // h stores acked at L3
    __syncthreads();                                  // B3: whole WG's h published
    if (t == 0)
      __hip_atomic_fetch_add(&flags[(wg & 7) * 32], 1, __ATOMIC_RELAXED, __HIP_MEMORY_SCOPE_AGENT);

    // out store off the critical path (after publish)
    *(floatx4*)&out[((size_t)b * 1024 + s) * 1024 + c0 + ci0] = (floatx4){hout[0], hout[1], hout[2], hout[3]};
  }

  *(floatx4*)&cstate[(size_t)b * 1024 + c0 + ci0] = c;
}

extern "C" void kernel_launch(void* const* d_in, const int* in_sizes, int n_in,
                              void* d_out, int out_size, void* d_ws, size_t ws_size,
                              hipStream_t stream)
{
  (void)in_sizes; (void)n_in; (void)out_size;
  const float* input_emb = (const float*)d_in[0];
  const float* W   = (const float*)d_in[1];
  const float* bWp = (const float*)d_in[2];
  const float* U   = (const float*)d_in[3];
  const float* bUp = (const float*)d_in[4];
  float* out   = (float*)d_out;
  float* hlast = out + (size_t)64 * 1024 * 1024;
  float* clast = hlast + 64 * 1024;

  char* base = (char*)d_ws;
  unsigned short* Wt = (unsigned short*)base;  base += 8388608;   // [4096][1024] bf16
  unsigned short* Ut = (unsigned short*)base;  base += 8388608;   // [4096][1024] bf16
  unsigned short* hb = (unsigned short*)base;  base += 262144;    // [2][64][1024] bf16
  float* cstate      = (float*)base;           base += 262144;    // [64][1024] f32
  int* flags         = (int*)base;             base += 8192;      // 8 x 128B counter lines
  size_t fixed = (size_t)(base - (char*)d_ws);
  size_t avail = ws_size > fixed ? ws_size - fixed : 0;
  int SC = 1024;                                // sequence chunk (adapt to ws)
  while (SC > 8 && (size_t)SC * 655360ull > avail) SC >>= 1;
  unsigned short* Abuf = (unsigned short*)base; base += (size_t)SC * 131072;  // [SC*64][1024] bf16
  unsigned short* xp   = (unsigned short*)base;                               // [SC*64][4096] bf16

  hipMemsetAsync(flags, 0, 8192, stream);
  hipMemsetAsync(hb, 0, 131072, stream);        // h0 = 0 (parity-0 buffer)

  k_transpose_bf16<<<dim3(16, 16, 4), 256, 0, stream>>>(W, Wt);
  k_transpose_bf16<<<dim3(16, 16, 4), 256, 0, stream>>>(U, Ut);

  int nch = 1024 / SC;
  for (int cc = 0; cc < nch; cc++){
    int s0 = cc * SC;
    k_convert_x<<<SC * 64, 256, 0, stream>>>(input_emb, Abuf, s0);
    k_gemm_xproj<<<dim3(SC / 2, 32), 256, 0, stream>>>(Abuf, Wt, bWp, bUp, xp);
    k_lstm_rec<<<64, 256, 0, stream>>>(xp, Ut, hb, cstate, out, hlast, clast, flags, s0, SC);
  }
}

// Round 3
// 10456.063 us; speedup vs baseline: 1.2795x; 1.2795x over previous
//
#include <hip/hip_runtime.h>
#include <hip/hip_bf16.h>
#include <stdint.h>

// LSTM B=64 S=1024 D=1024 H=1024, gates f,i,o,g all sigmoid.
// Phase 1: xproj = x@W + bW + bU  (bf16 MFMA GEMM)
// Phase 2: persistent recurrent kernel, 64 WGs (one per 16 h-cols), 4 waves = 4 gates.
//   U fragments resident in VGPRs (128 regs), h staged to LDS via global_load_lds,
//   producer h-stores = agent atomics (-> L3), consumer = acquire fence + cached loads
//   (h shared through XCD-local L2: 1 MB/step from L3 instead of 8 MB).

typedef __attribute__((ext_vector_type(8))) short short8;
typedef __attribute__((ext_vector_type(4))) float floatx4;

__device__ __forceinline__ unsigned short f2bf(float x){
  union { float f; unsigned int u; } v; v.f = x;
  unsigned int r = v.u + 0x7fffu + ((v.u >> 16) & 1u);
  return (unsigned short)(r >> 16);
}
__device__ __forceinline__ float bf2f(unsigned short b){
  union { unsigned int u; float f; } v; v.u = ((unsigned int)b) << 16; return v.f;
}
__device__ __forceinline__ float fsigmoid(float x){ return 1.0f / (1.0f + __expf(-x)); }
__device__ __forceinline__ float ftanh(float x){ return 1.0f - 2.0f / (1.0f + __expf(2.0f * x)); }

// ---- transpose [g][d][h] fp32 -> [g][h][d] bf16 (per-gate 1024x1024) ----
__global__ void k_transpose_bf16(const float* __restrict__ src, unsigned short* __restrict__ dst){
  __shared__ float tile[64][65];
  const int g  = blockIdx.z;
  const int d0 = blockIdx.x * 64;
  const int h0 = blockIdx.y * 64;
  const int t  = threadIdx.x;
  const float* s    = src + ((size_t)g << 20);
  unsigned short* o = dst + ((size_t)g << 20);
  #pragma unroll
  for (int i = 0; i < 16; i++){
    int e = i * 256 + t;
    int r = e >> 6, c = e & 63;
    tile[r][c] = s[(size_t)(d0 + r) * 1024 + (h0 + c)];
  }
  __syncthreads();
  #pragma unroll
  for (int i = 0; i < 16; i++){
    int e = i * 256 + t;
    int a = e >> 6, bb = e & 63;
    o[(size_t)(h0 + a) * 1024 + (d0 + bb)] = f2bf(tile[bb][a]);
  }
}

// ---- convert input chunk (B,S,D) fp32 -> Abuf[(sl*64+b)][d] bf16 ----
__global__ void k_convert_x(const float* __restrict__ inp, unsigned short* __restrict__ abuf, int s0){
  int idx = blockIdx.x * 256 + threadIdx.x;
  int e = idx * 4;
  int r = e >> 10, d = e & 1023;
  int b = r & 63, sl = r >> 6;
  floatx4 v = *(const floatx4*)(inp + ((size_t)(b * 1024 + (s0 + sl)) * 1024 + d));
  unsigned long long pk = (unsigned long long)f2bf(v[0])
                        | ((unsigned long long)f2bf(v[1]) << 16)
                        | ((unsigned long long)f2bf(v[2]) << 32)
                        | ((unsigned long long)f2bf(v[3]) << 48);
  *(unsigned long long*)(abuf + (size_t)r * 1024 + d) = pk;
}

// ---- xproj GEMM: C[M][4096] = A[M][1024] @ Bt^T + (bW+bU), bf16 out ----
__global__ void __launch_bounds__(256) k_gemm_xproj(
    const unsigned short* __restrict__ A,
    const unsigned short* __restrict__ Bt,
    const float* __restrict__ bW,
    const float* __restrict__ bU,
    unsigned short* __restrict__ Cc)
{
  __shared__ unsigned short As[2][128][64];
  __shared__ unsigned short Bs[2][128][64];
  const int t = threadIdx.x;
  const int w = t >> 6;
  const int lane = t & 63;
  const int m0 = blockIdx.x * 128;
  const int n0 = blockIdx.y * 128;
  floatx4 acc[4][4];
  #pragma unroll
  for (int i = 0; i < 4; i++)
    #pragma unroll
    for (int j = 0; j < 4; j++)
      acc[i][j] = (floatx4){0.f, 0.f, 0.f, 0.f};

  auto stage = [&](int bufi, int kt){
    #pragma unroll
    for (int i = 0; i < 4; i++){
      int chunk = i * 256 + t;
      int r = chunk >> 3, j = chunk & 7;
      int js = j ^ (r & 7);
      __builtin_amdgcn_global_load_lds(
        (const __attribute__((address_space(1))) unsigned int*)(A + (size_t)(m0 + r) * 1024 + kt * 64 + js * 8),
        (__attribute__((address_space(3))) unsigned int*)(&As[bufi][0][0] + (i * 256 + w * 64) * 8), 16, 0, 0);
    }
    #pragma unroll
    for (int i = 0; i < 4; i++){
      int chunk = i * 256 + t;
      int r = chunk >> 3, j = chunk & 7;
      int js = j ^ (r & 7);
      __builtin_amdgcn_global_load_lds(
        (const __attribute__((address_space(1))) unsigned int*)(Bt + (size_t)(n0 + r) * 1024 + kt * 64 + js * 8),
        (__attribute__((address_space(3))) unsigned int*)(&Bs[bufi][0][0] + (i * 256 + w * 64) * 8), 16, 0, 0);
    }
  };

  auto compute = [&](int bufi){
    const int mi0 = (w >> 1) * 64;
    const int ni0 = (w & 1) * 64;
    #pragma unroll
    for (int kc = 0; kc < 2; kc++){
      short8 af[4], bfr[4];
      #pragma unroll
      for (int mi = 0; mi < 4; mi++){
        int row = mi0 + mi * 16 + (lane & 15);
        int j = kc * 4 + (lane >> 4);
        af[mi] = *(const short8*)&As[bufi][row][(j ^ (row & 7)) * 8];
      }
      #pragma unroll
      for (int ni = 0; ni < 4; ni++){
        int row = ni0 + ni * 16 + (lane & 15);
        int j = kc * 4 + (lane >> 4);
        bfr[ni] = *(const short8*)&Bs[bufi][row][(j ^ (row & 7)) * 8];
      }
      #pragma unroll
      for (int mi = 0; mi < 4; mi++)
        #pragma unroll
        for (int ni = 0; ni < 4; ni++)
          acc[mi][ni] = __builtin_amdgcn_mfma_f32_16x16x32_bf16(af[mi], bfr[ni], acc[mi][ni], 0, 0, 0);
    }
  };

  stage(0, 0);
  int buf = 0;
  for (int kt = 0; kt < 16; kt++){
    __syncthreads();
    if (kt < 15) stage(buf ^ 1, kt + 1);
    compute(buf);
    buf ^= 1;
  }

  {
    const int mi0 = (w >> 1) * 64;
    const int ni0 = (w & 1) * 64;
    #pragma unroll
    for (int ni = 0; ni < 4; ni++){
      int col = n0 + ni0 + ni * 16 + (lane & 15);
      float bias = bW[col] + bU[col];
      #pragma unroll
      for (int mi = 0; mi < 4; mi++){
        int mrow = m0 + mi0 + mi * 16 + (lane >> 4) * 4;
        #pragma unroll
        for (int r = 0; r < 4; r++)
          Cc[(size_t)(mrow + r) * 4096 + col] = f2bf(acc[mi][ni][r] + bias);
      }
    }
  }
}

// ---- persistent recurrent kernel ----
// hb2 layout (per parity): tile [k>>4][b][k&15] bf16 (k = global h-col 0..1023).
// WG wg owns h-cols [wg*16, wg*16+16) => writes tile chunk [wg][b][0..15] (2KB contiguous).
__global__ void __launch_bounds__(256, 1) k_lstm_rec(
    const unsigned short* __restrict__ xp,   // [SC*64][4096] bf16
    const unsigned short* __restrict__ Ut,   // [4096][1024] bf16 (gate-major rows)
    unsigned short* hb2,                     // [2][64][64][16] bf16
    float* cstate,                           // [64][1024]
    float* __restrict__ out,                 // (B,S,H) fp32
    float* __restrict__ hlast,
    float* __restrict__ clast,
    int* flags,                              // 8 counter lines, stride 32 ints
    int s_base, int SC)
{
  const int t = threadIdx.x;
  const int w = t >> 6;          // wave = gate
  const int lane = t & 63;
  const int wg = blockIdx.x;
  const int c0 = wg * 16;

  __shared__ unsigned short hsh[64][1024];   // 128 KB staged h (XOR-swizzled rows)
  __shared__ float glds[4][64][20];          // 20.5 KB gate exchange (pad 20)

  // U fragments resident in VGPRs: wave w = gate w, cols c0..c0+15, full K=1024.
  // B-frag (16x16x32): lane holds B[k=(l>>4)*8+j][n=l&15]; Ut row = w*1024+c0+(l&15).
  short8 bfrag[32];
  {
    const unsigned short* bp = Ut + (size_t)(w * 1024 + c0 + (lane & 15)) * 1024 + (lane >> 4) * 8;
    #pragma unroll
    for (int kc = 0; kc < 32; kc++)
      bfrag[kc] = *(const short8*)(bp + kc * 32);
  }

  const int b = t >> 2;            // batch owned in epilogue
  const int ci0 = (t & 3) * 4;     // 4 h-cols owned
  floatx4 c;
  if (s_base == 0) c = (floatx4){0.f, 0.f, 0.f, 0.f};
  else             c = *(const floatx4*)&cstate[(size_t)b * 1024 + c0 + ci0];

  int bail = 20000000;

  for (int sl = 0; sl < SC; sl++){
    const int s = s_base + sl;
    const int p = s & 1;

    // xp prefetch (independent of h) before the spin
    unsigned long long xv[4];
    #pragma unroll
    for (int g = 0; g < 4; g++)
      xv[g] = *(const unsigned long long*)(xp + ((size_t)(sl * 64 + b)) * 4096 + g * 1024 + c0 + ci0);
    __builtin_amdgcn_sched_barrier(0);

    if (sl > 0 && w == 0){
      const int* cp = &flags[(lane & 7) * 32];
      const int target = 8 * s;
      while (__hip_atomic_load(cp, __ATOMIC_RELAXED, __HIP_MEMORY_SCOPE_AGENT) < target){
        __builtin_amdgcn_s_sleep(1);
        if (--bail < 0) break;
      }
    }
    __syncthreads();                                    // B1
    __builtin_amdgcn_fence(__ATOMIC_ACQUIRE, "agent");  // invalidate L1/L2 (U is in VGPRs, cheap)

    // stage h[64][1024] into LDS, XOR-swizzled rows; cached loads -> L2-shared per XCD
    {
      const char* hsrc = (const char*)hb2 + (size_t)p * 131072;
      const int bst = (w >> 1);            // wave-uniform part of batch row
      const int half = (w & 1) * 1024;     // which 1 KB half of the row
      #pragma unroll
      for (int i = 0; i < 32; i++){
        const int brow = i * 2 + bst;
        const int bb = half + lane * 16;                 // dest byte within row
        const int bbs = bb ^ ((brow & 7) << 4);          // swizzled logical byte
        // logical h[brow][k]: tile byte = ((bbs>>5)*64 + brow)*32 + (bbs&31)
        const char* src = hsrc + (((bbs >> 5) * 64 + brow) << 5) + (bbs & 31);
        __builtin_amdgcn_global_load_lds(
          (const __attribute__((address_space(1))) unsigned int*)src,
          (__attribute__((address_space(3))) unsigned int*)(&hsh[0][0] + ((size_t)brow * 1024 + half / 2) + lane * 8),
          16, 0, 0);
      }
    }
    __syncthreads();                                    // B2 (drains vmcnt + lds)

    // GEMM: acc[mi] = h[64 x 1024] @ U_w[1024 x 16]
    floatx4 acc[4];
    #pragma unroll
    for (int i = 0; i < 4; i++) acc[i] = (floatx4){0.f, 0.f, 0.f, 0.f};

    #pragma unroll
    for (int kc = 0; kc < 32; kc++){
      short8 af[4];
      #pragma unroll
      for (int mi = 0; mi < 4; mi++){
        const int row = mi * 16 + (lane & 15);
        const int byt = (kc * 64 + (lane >> 4) * 16) ^ ((row & 7) << 4);
        af[mi] = *(const short8*)((const char*)&hsh[row][0] + byt);
      }
      #pragma unroll
      for (int mi = 0; mi < 4; mi++)
        acc[mi] = __builtin_amdgcn_mfma_f32_16x16x32_bf16(af[mi], bfrag[kc], acc[mi], 0, 0, 0);
    }

    // publish gate values: glds[gate][batch][hcol]  (C: row=(l>>4)*4+r = batch, col=l&15)
    #pragma unroll
    for (int mi = 0; mi < 4; mi++)
      #pragma unroll
      for (int r = 0; r < 4; r++)
        glds[w][mi * 16 + (lane >> 4) * 4 + r][lane & 15] = acc[mi][r];
    __syncthreads();                                    // B3

    // epilogue: thread owns (b, ci0..ci0+3)
    float hout[4];
    {
      floatx4 gs[4];
      #pragma unroll
      for (int g = 0; g < 4; g++){
        gs[g] = *(const floatx4*)&glds[g][b][ci0];
        gs[g][0] += bf2f((unsigned short)(xv[g]));
        gs[g][1] += bf2f((unsigned short)(xv[g] >> 16));
        gs[g][2] += bf2f((unsigned short)(xv[g] >> 32));
        gs[g][3] += bf2f((unsigned short)(xv[g] >> 48));
      }
      #pragma unroll
      for (int j = 0; j < 4; j++){
        float fv = fsigmoid(gs[0][j]);
        float iv = fsigmoid(gs[1][j]);
        float ov = fsigmoid(gs[2][j]);
        float gv = fsigmoid(gs[3][j]);   // reference: sigmoid, not tanh
        float cv = fv * c[j] + iv * gv;
        c[j] = cv;
        hout[j] = ov * ftanh(cv);
      }
    }

    // publish h slice: agent atomic store -> L3 (tile layout, thread t at byte wg*2048+t*8)
    unsigned long long hpk = (unsigned long long)f2bf(hout[0])
                           | ((unsigned long long)f2bf(hout[1]) << 16)
                           | ((unsigned long long)f2bf(hout[2]) << 32)
                           | ((unsigned long long)f2bf(hout[3]) << 48);
    __hip_atomic_store((unsigned long long*)((char*)hb2 + (size_t)(p ^ 1) * 131072 + wg * 2048 + t * 8),
                       hpk, __ATOMIC_RELAXED, __HIP_MEMORY_SCOPE_AGENT);

    if (s == 1023){
      *(floatx4*)&hlast[(size_t)b * 1024 + c0 + ci0] = (floatx4){hout[0], hout[1], hout[2], hout[3]};
      *(floatx4*)&clast[(size_t)b * 1024 + c0 + ci0] = c;
    }

    __syncthreads();                                    // B4: all h stores drained (vmcnt)
    if (t == 0)
      __hip_atomic_fetch_add(&flags[(wg & 7) * 32], 1, __ATOMIC_RELAXED, __HIP_MEMORY_SCOPE_AGENT);

    // out store off the critical path
    *(floatx4*)&out[((size_t)b * 1024 + s) * 1024 + c0 + ci0] = (floatx4){hout[0], hout[1], hout[2], hout[3]};
  }

  *(floatx4*)&cstate[(size_t)b * 1024 + c0 + ci0] = c;
}

extern "C" void kernel_launch(void* const* d_in, const int* in_sizes, int n_in,
                              void* d_out, int out_size, void* d_ws, size_t ws_size,
                              hipStream_t stream)
{
  (void)in_sizes; (void)n_in; (void)out_size;
  const float* input_emb = (const float*)d_in[0];
  const float* W   = (const float*)d_in[1];
  const float* bWp = (const float*)d_in[2];
  const float* U   = (const float*)d_in[3];
  const float* bUp = (const float*)d_in[4];
  float* out   = (float*)d_out;
  float* hlast = out + (size_t)64 * 1024 * 1024;
  float* clast = hlast + 64 * 1024;

  char* base = (char*)d_ws;
  unsigned short* Wt  = (unsigned short*)base;  base += 8388608;   // [4096][1024] bf16
  unsigned short* Ut  = (unsigned short*)base;  base += 8388608;   // [4096][1024] bf16
  unsigned short* hb2 = (unsigned short*)base;  base += 262144;    // [2][64][64][16] bf16
  float* cstate       = (float*)base;           base += 262144;    // [64][1024] f32
  int* flags          = (int*)base;             base += 8192;      // 8 x 128B counter lines
  size_t fixed = (size_t)(base - (char*)d_ws);
  size_t avail = ws_size > fixed ? ws_size - fixed : 0;
  int SC = 1024;
  while (SC > 8 && (size_t)SC * 655360ull > avail) SC >>= 1;
  unsigned short* Abuf = (unsigned short*)base; base += (size_t)SC * 131072;  // [SC*64][1024] bf16
  unsigned short* xpb  = (unsigned short*)base;                               // [SC*64][4096] bf16

  hipMemsetAsync(flags, 0, 8192, stream);
  hipMemsetAsync(hb2, 0, 131072, stream);       // h0 = 0 (parity-0 buffer)

  k_transpose_bf16<<<dim3(16, 16, 4), 256, 0, stream>>>(W, Wt);
  k_transpose_bf16<<<dim3(16, 16, 4), 256, 0, stream>>>(U, Ut);

  int nch = 1024 / SC;
  for (int cc = 0; cc < nch; cc++){
    int s0 = cc * SC;
    k_convert_x<<<SC * 64, 256, 0, stream>>>(input_emb, Abuf, s0);
    k_gemm_xproj<<<dim3(SC / 2, 32), 256, 0, stream>>>(Abuf, Wt, bWp, bUp, xpb);
    k_lstm_rec<<<64, 256, 0, stream>>>(xpb, Ut, hb2, cstate, out, hlast, clast, flags, s0, SC);
  }
}

// Round 4
// 10351.002 us; speedup vs baseline: 1.2925x; 1.0101x over previous
//
#include <hip/hip_runtime.h>
#include <hip/hip_bf16.h>
#include <stdint.h>

// LSTM B=64 S=1024 D=1024 H=1024, gates f,i,o,g all sigmoid.
// Phase 1: xproj = x@W + bW + bU  (bf16 MFMA GEMM)
// Phase 2: persistent recurrent kernel, 64 WGs (one per 16 h-cols), 4 waves = 4 gates.
//   U resident in VGPRs (128 regs/lane). h staged to LDS in MFMA-subtile layout
//   (conflict-free contiguous ds_read_b128). h publish = coalesced sc0sc1 stores -> L3.
//   Barrier: 64 contiguous flag ints, coalesced 64-lane poll + __all.

typedef __attribute__((ext_vector_type(8))) short short8;
typedef __attribute__((ext_vector_type(4))) float floatx4;
typedef __attribute__((ext_vector_type(2))) unsigned int uint2v;

__device__ __forceinline__ unsigned short f2bf(float x){
  union { float f; unsigned int u; } v; v.f = x;
  unsigned int r = v.u + 0x7fffu + ((v.u >> 16) & 1u);
  return (unsigned short)(r >> 16);
}
__device__ __forceinline__ float bf2f(unsigned short b){
  union { unsigned int u; float f; } v; v.u = ((unsigned int)b) << 16; return v.f;
}
__device__ __forceinline__ float fsigmoid(float x){ return 1.0f / (1.0f + __expf(-x)); }
__device__ __forceinline__ float ftanh(float x){ return 1.0f - 2.0f / (1.0f + __expf(2.0f * x)); }

// ---- transpose [g][d][h] fp32 -> [g][h][d] bf16 (per-gate 1024x1024) ----
__global__ void k_transpose_bf16(const float* __restrict__ src, unsigned short* __restrict__ dst){
  __shared__ float tile[64][65];
  const int g  = blockIdx.z;
  const int d0 = blockIdx.x * 64;
  const int h0 = blockIdx.y * 64;
  const int t  = threadIdx.x;
  const float* s    = src + ((size_t)g << 20);
  unsigned short* o = dst + ((size_t)g << 20);
  #pragma unroll
  for (int i = 0; i < 16; i++){
    int e = i * 256 + t;
    int r = e >> 6, c = e & 63;
    tile[r][c] = s[(size_t)(d0 + r) * 1024 + (h0 + c)];
  }
  __syncthreads();
  #pragma unroll
  for (int i = 0; i < 16; i++){
    int e = i * 256 + t;
    int a = e >> 6, bb = e & 63;
    o[(size_t)(h0 + a) * 1024 + (d0 + bb)] = f2bf(tile[bb][a]);
  }
}

// ---- convert input chunk (B,S,D) fp32 -> Abuf[(sl*64+b)][d] bf16 ----
__global__ void k_convert_x(const float* __restrict__ inp, unsigned short* __restrict__ abuf, int s0){
  int idx = blockIdx.x * 256 + threadIdx.x;
  int e = idx * 4;
  int r = e >> 10, d = e & 1023;
  int b = r & 63, sl = r >> 6;
  floatx4 v = *(const floatx4*)(inp + ((size_t)(b * 1024 + (s0 + sl)) * 1024 + d));
  unsigned long long pk = (unsigned long long)f2bf(v[0])
                        | ((unsigned long long)f2bf(v[1]) << 16)
                        | ((unsigned long long)f2bf(v[2]) << 32)
                        | ((unsigned long long)f2bf(v[3]) << 48);
  *(unsigned long long*)(abuf + (size_t)r * 1024 + d) = pk;
}

// ---- xproj GEMM: C[M][4096] = A[M][1024] @ Bt^T + (bW+bU), bf16 out ----
__global__ void __launch_bounds__(256) k_gemm_xproj(
    const unsigned short* __restrict__ A,
    const unsigned short* __restrict__ Bt,
    const float* __restrict__ bW,
    const float* __restrict__ bU,
    unsigned short* __restrict__ Cc)
{
  __shared__ unsigned short As[2][128][64];
  __shared__ unsigned short Bs[2][128][64];
  const int t = threadIdx.x;
  const int w = t >> 6;
  const int lane = t & 63;
  const int m0 = blockIdx.x * 128;
  const int n0 = blockIdx.y * 128;
  floatx4 acc[4][4];
  #pragma unroll
  for (int i = 0; i < 4; i++)
    #pragma unroll
    for (int j = 0; j < 4; j++)
      acc[i][j] = (floatx4){0.f, 0.f, 0.f, 0.f};

  auto stage = [&](int bufi, int kt){
    #pragma unroll
    for (int i = 0; i < 4; i++){
      int chunk = i * 256 + t;
      int r = chunk >> 3, j = chunk & 7;
      int js = j ^ (r & 7);
      __builtin_amdgcn_global_load_lds(
        (const __attribute__((address_space(1))) unsigned int*)(A + (size_t)(m0 + r) * 1024 + kt * 64 + js * 8),
        (__attribute__((address_space(3))) unsigned int*)(&As[bufi][0][0] + (i * 256 + w * 64) * 8), 16, 0, 0);
    }
    #pragma unroll
    for (int i = 0; i < 4; i++){
      int chunk = i * 256 + t;
      int r = chunk >> 3, j = chunk & 7;
      int js = j ^ (r & 7);
      __builtin_amdgcn_global_load_lds(
        (const __attribute__((address_space(1))) unsigned int*)(Bt + (size_t)(n0 + r) * 1024 + kt * 64 + js * 8),
        (__attribute__((address_space(3))) unsigned int*)(&Bs[bufi][0][0] + (i * 256 + w * 64) * 8), 16, 0, 0);
    }
  };

  auto compute = [&](int bufi){
    const int mi0 = (w >> 1) * 64;
    const int ni0 = (w & 1) * 64;
    #pragma unroll
    for (int kc = 0; kc < 2; kc++){
      short8 af[4], bfr[4];
      #pragma unroll
      for (int mi = 0; mi < 4; mi++){
        int row = mi0 + mi * 16 + (lane & 15);
        int j = kc * 4 + (lane >> 4);
        af[mi] = *(const short8*)&As[bufi][row][(j ^ (row & 7)) * 8];
      }
      #pragma unroll
      for (int ni = 0; ni < 4; ni++){
        int row = ni0 + ni * 16 + (lane & 15);
        int j = kc * 4 + (lane >> 4);
        bfr[ni] = *(const short8*)&Bs[bufi][row][(j ^ (row & 7)) * 8];
      }
      #pragma unroll
      for (int mi = 0; mi < 4; mi++)
        #pragma unroll
        for (int ni = 0; ni < 4; ni++)
          acc[mi][ni] = __builtin_amdgcn_mfma_f32_16x16x32_bf16(af[mi], bfr[ni], acc[mi][ni], 0, 0, 0);
    }
  };

  stage(0, 0);
  int buf = 0;
  for (int kt = 0; kt < 16; kt++){
    __syncthreads();
    if (kt < 15) stage(buf ^ 1, kt + 1);
    compute(buf);
    buf ^= 1;
  }

  {
    const int mi0 = (w >> 1) * 64;
    const int ni0 = (w & 1) * 64;
    #pragma unroll
    for (int ni = 0; ni < 4; ni++){
      int col = n0 + ni0 + ni * 16 + (lane & 15);
      float bias = bW[col] + bU[col];
      #pragma unroll
      for (int mi = 0; mi < 4; mi++){
        int mrow = m0 + mi0 + mi * 16 + (lane >> 4) * 4;
        #pragma unroll
        for (int r = 0; r < 4; r++)
          Cc[(size_t)(mrow + r) * 4096 + col] = f2bf(acc[mi][ni][r] + bias);
      }
    }
  }
}

// ---- persistent recurrent kernel ----
// hb2 (per parity): tile [k>>4][b][k&15] bf16.  WG wg writes chunk [wg][b][0..15].
// hsh LDS layout: 128 subtiles of 1024B, subtile st = kc*4+mi holds the MFMA A-frag
// for (kc, mi): element (b = mi*16+r, k = kc*32+j*8+e) at byte st*1024 + (j*16+r)*16 + e*2.
// => ds_read_b128 at st*1024 + lane*16 is contiguous & conflict-free.
__global__ void __launch_bounds__(256, 1) k_lstm_rec(
    const unsigned short* __restrict__ xp,   // [SC*64][4096] bf16
    const unsigned short* __restrict__ Ut,   // [4096][1024] bf16 (gate-major rows)
    unsigned short* hb2,                     // [2][64][64][16] bf16
    float* cstate,                           // [64][1024]
    float* __restrict__ out,                 // (B,S,H) fp32
    float* __restrict__ hlast,
    float* __restrict__ clast,
    int* flags,                              // 64 contiguous ints
    int s_base, int SC)
{
  const int t = threadIdx.x;
  const int w = t >> 6;          // wave = gate
  const int lane = t & 63;
  const int wg = blockIdx.x;
  const int c0 = wg * 16;

  __shared__ unsigned short hsh[128][512];   // 128 KB, viewed as 128 x 1024B subtiles
  __shared__ float glds[4][64][20];          // gate exchange (pad 20)

  // U fragments in VGPRs: wave w = gate w, cols c0..c0+15, full K=1024.
  short8 bfrag[32];
  {
    const unsigned short* bp = Ut + (size_t)(w * 1024 + c0 + (lane & 15)) * 1024 + (lane >> 4) * 8;
    #pragma unroll
    for (int kc = 0; kc < 32; kc++)
      bfrag[kc] = *(const short8*)(bp + kc * 32);
  }

  const int b = t >> 2;            // batch owned in epilogue
  const int ci0 = (t & 3) * 4;     // 4 h-cols owned
  floatx4 c;
  if (s_base == 0) c = (floatx4){0.f, 0.f, 0.f, 0.f};
  else             c = *(const floatx4*)&cstate[(size_t)b * 1024 + c0 + ci0];

  int bail = 20000000;

  const int j = lane >> 4, r = lane & 15;

  for (int sl = 0; sl < SC; sl++){
    const int s = s_base + sl;
    const int p = s & 1;

    // xp prefetch (independent of h) before the spin
    unsigned long long xv[4];
    #pragma unroll
    for (int g = 0; g < 4; g++)
      xv[g] = *(const unsigned long long*)(xp + ((size_t)(sl * 64 + b)) * 4096 + g * 1024 + c0 + ci0);
    __builtin_amdgcn_sched_barrier(0);

    if (sl > 0 && w == 0){
      // coalesced poll: lane l watches flags[l]
      while (true){
        int v = __hip_atomic_load(&flags[lane], __ATOMIC_RELAXED, __HIP_MEMORY_SCOPE_AGENT);
        if (__all(v >= s)) break;
        __builtin_amdgcn_s_sleep(2);
        if (--bail < 0) break;
      }
    }
    __syncthreads();                                    // B1
    __builtin_amdgcn_fence(__ATOMIC_ACQUIRE, "agent");  // invalidate L1/L2 (U in VGPRs, cheap)

    // stage h into subtiled LDS; wave w stages subtiles [w*32, w*32+32)
    {
      const char* hsrc = (const char*)hb2 + (size_t)p * 131072;
      #pragma unroll
      for (int i = 0; i < 32; i++){
        const int st = w * 32 + i;
        const int kc = st >> 2, mi = st & 3;
        // lane (j,r) fetches h[mi*16+r][kc*32+j*8 .. +7] from tile layout
        const char* src = hsrc + (((kc * 2 + (j >> 1)) * 64 + mi * 16 + r) << 5) + ((j & 1) << 4);
        __builtin_amdgcn_global_load_lds(
          (const __attribute__((address_space(1))) unsigned int*)src,
          (__attribute__((address_space(3))) unsigned int*)((char*)&hsh[0][0] + (size_t)st * 1024),
          16, 0, 0);
      }
    }
    __syncthreads();                                    // B2 (drains vmcnt + lds)

    // GEMM: acc[mi] = h[64 x 1024] @ U_w[1024 x 16]; A-frags contiguous in LDS
    floatx4 acc[4];
    #pragma unroll
    for (int i = 0; i < 4; i++) acc[i] = (floatx4){0.f, 0.f, 0.f, 0.f};

    const char* hp = (const char*)&hsh[0][0] + lane * 16;
    #pragma unroll
    for (int kc = 0; kc < 32; kc++){
      short8 af[4];
      #pragma unroll
      for (int mi = 0; mi < 4; mi++)
        af[mi] = *(const short8*)(hp + (size_t)(kc * 4 + mi) * 1024);
      #pragma unroll
      for (int mi = 0; mi < 4; mi++)
        acc[mi] = __builtin_amdgcn_mfma_f32_16x16x32_bf16(af[mi], bfrag[kc], acc[mi], 0, 0, 0);
    }

    // publish gate values: glds[gate][batch][hcol]  (C: row=(l>>4)*4+r2, col=l&15)
    #pragma unroll
    for (int mi = 0; mi < 4; mi++)
      #pragma unroll
      for (int r2 = 0; r2 < 4; r2++)
        glds[w][mi * 16 + (lane >> 4) * 4 + r2][lane & 15] = acc[mi][r2];
    __syncthreads();                                    // B3

    // epilogue: thread owns (b, ci0..ci0+3)
    float hout[4];
    {
      floatx4 gs[4];
      #pragma unroll
      for (int g = 0; g < 4; g++){
        gs[g] = *(const floatx4*)&glds[g][b][ci0];
        gs[g][0] += bf2f((unsigned short)(xv[g]));
        gs[g][1] += bf2f((unsigned short)(xv[g] >> 16));
        gs[g][2] += bf2f((unsigned short)(xv[g] >> 32));
        gs[g][3] += bf2f((unsigned short)(xv[g] >> 48));
      }
      #pragma unroll
      for (int jj = 0; jj < 4; jj++){
        float fv = fsigmoid(gs[0][jj]);
        float iv = fsigmoid(gs[1][jj]);
        float ov = fsigmoid(gs[2][jj]);
        float gv = fsigmoid(gs[3][jj]);   // reference: sigmoid, not tanh
        float cv = fv * c[jj] + iv * gv;
        c[jj] = cv;
        hout[jj] = ov * ftanh(cv);
      }
    }

    // publish h slice: coalesced write-through stores (sc0 sc1 -> L3)
    {
      uint2v hv;
      hv.x = (unsigned int)f2bf(hout[0]) | ((unsigned int)f2bf(hout[1]) << 16);
      hv.y = (unsigned int)f2bf(hout[2]) | ((unsigned int)f2bf(hout[3]) << 16);
      void* dst = (char*)hb2 + (size_t)(p ^ 1) * 131072 + wg * 2048 + t * 8;
      asm volatile("global_store_dwordx2 %0, %1, off sc0 sc1" :: "v"(dst), "v"(hv) : "memory");
    }

    if (s == 1023){
      *(floatx4*)&hlast[(size_t)b * 1024 + c0 + ci0] = (floatx4){hout[0], hout[1], hout[2], hout[3]};
      *(floatx4*)&clast[(size_t)b * 1024 + c0 + ci0] = c;
    }

    asm volatile("s_waitcnt vmcnt(0)" ::: "memory");    // this wave's h stores acked at L3
    __syncthreads();                                    // B4: all waves drained
    if (t == 0)
      __hip_atomic_store(&flags[wg], s + 1, __ATOMIC_RELAXED, __HIP_MEMORY_SCOPE_AGENT);

    // out store off the critical path
    *(floatx4*)&out[((size_t)b * 1024 + s) * 1024 + c0 + ci0] = (floatx4){hout[0], hout[1], hout[2], hout[3]};
  }

  *(floatx4*)&cstate[(size_t)b * 1024 + c0 + ci0] = c;
}

extern "C" void kernel_launch(void* const* d_in, const int* in_sizes, int n_in,
                              void* d_out, int out_size, void* d_ws, size_t ws_size,
                              hipStream_t stream)
{
  (void)in_sizes; (void)n_in; (void)out_size;
  const float* input_emb = (const float*)d_in[0];
  const float* W   = (const float*)d_in[1];
  const float* bWp = (const float*)d_in[2];
  const float* U   = (const float*)d_in[3];
  const float* bUp = (const float*)d_in[4];
  float* out   = (float*)d_out;
  float* hlast = out + (size_t)64 * 1024 * 1024;
  float* clast = hlast + 64 * 1024;

  char* base = (char*)d_ws;
  unsigned short* Wt  = (unsigned short*)base;  base += 8388608;   // [4096][1024] bf16
  unsigned short* Ut  = (unsigned short*)base;  base += 8388608;   // [4096][1024] bf16
  unsigned short* hb2 = (unsigned short*)base;  base += 262144;    // [2][64][64][16] bf16
  float* cstate       = (float*)base;           base += 262144;    // [64][1024] f32
  int* flags          = (int*)base;             base += 8192;      // 64 contiguous ints (+pad)
  size_t fixed = (size_t)(base - (char*)d_ws);
  size_t avail = ws_size > fixed ? ws_size - fixed : 0;
  int SC = 1024;
  while (SC > 8 && (size_t)SC * 655360ull > avail) SC >>= 1;
  unsigned short* Abuf = (unsigned short*)base; base += (size_t)SC * 131072;  // [SC*64][1024] bf16
  unsigned short* xpb  = (unsigned short*)base;                               // [SC*64][4096] bf16

  hipMemsetAsync(flags, 0, 8192, stream);
  hipMemsetAsync(hb2, 0, 131072, stream);       // h0 = 0 (parity-0 buffer)

  k_transpose_bf16<<<dim3(16, 16, 4), 256, 0, stream>>>(W, Wt);
  k_transpose_bf16<<<dim3(16, 16, 4), 256, 0, stream>>>(U, Ut);

  int nch = 1024 / SC;
  for (int cc = 0; cc < nch; cc++){
    int s0 = cc * SC;
    k_convert_x<<<SC * 64, 256, 0, stream>>>(input_emb, Abuf, s0);
    k_gemm_xproj<<<dim3(SC / 2, 32), 256, 0, stream>>>(Abuf, Wt, bWp, bUp, xpb);
    k_lstm_rec<<<64, 256, 0, stream>>>(xpb, Ut, hb2, cstate, out, hlast, clast, flags, s0, SC);
  }
}

// Round 10
// 10157.609 us; speedup vs baseline: 1.3171x; 1.0190x over previous
//
#include <hip/hip_runtime.h>
#include <hip/hip_bf16.h>
#include <stdint.h>

// LSTM B=64 S=1024 D=1024 H=1024, gates f,i,o,g all sigmoid.
// Phase 1: xproj = x@W + bW + bU  (bf16 MFMA GEMM)
// Phase 2: persistent recurrent kernel, 128 WGs = 4 batch-groups x 32 col-WGs.
//   Group g owns batches 16g..16g+15 (M=16, NO padding). WG j owns 32 h-cols;
//   U slice in VGPRs (256 regs/lane). GLOBAL lockstep barrier (R4-proven scope).
//   Publish: per-thread 4B sc0sc1 stores direct from registers into A-frag subtile
//   layout (R4's exact store mechanism; every subtile fully rewritten each step).
//   Consume: acquire fence + linear global_load_lds (R4's exact stage mechanism).

typedef __attribute__((ext_vector_type(8))) short short8;
typedef __attribute__((ext_vector_type(4))) float floatx4;
typedef __attribute__((ext_vector_type(2))) float floatx2;

__device__ __forceinline__ unsigned short f2bf(float x){
  union { float f; unsigned int u; } v; v.f = x;
  unsigned int r = v.u + 0x7fffu + ((v.u >> 16) & 1u);
  return (unsigned short)(r >> 16);
}
__device__ __forceinline__ float bf2f(unsigned short b){
  union { unsigned int u; float f; } v; v.u = ((unsigned int)b) << 16; return v.f;
}
__device__ __forceinline__ float fsigmoid(float x){ return 1.0f / (1.0f + __expf(-x)); }
__device__ __forceinline__ float ftanh(float x){ return 1.0f - 2.0f / (1.0f + __expf(2.0f * x)); }

// ---- transpose [g][d][h] fp32 -> [g][h][d] bf16 (per-gate 1024x1024) ----
__global__ void k_transpose_bf16(const float* __restrict__ src, unsigned short* __restrict__ dst){
  __shared__ float tile[64][65];
  const int g  = blockIdx.z;
  const int d0 = blockIdx.x * 64;
  const int h0 = blockIdx.y * 64;
  const int t  = threadIdx.x;
  const float* s    = src + ((size_t)g << 20);
  unsigned short* o = dst + ((size_t)g << 20);
  #pragma unroll
  for (int i = 0; i < 16; i++){
    int e = i * 256 + t;
    int r = e >> 6, c = e & 63;
    tile[r][c] = s[(size_t)(d0 + r) * 1024 + (h0 + c)];
  }
  __syncthreads();
  #pragma unroll
  for (int i = 0; i < 16; i++){
    int e = i * 256 + t;
    int a = e >> 6, bb = e & 63;
    o[(size_t)(h0 + a) * 1024 + (d0 + bb)] = f2bf(tile[bb][a]);
  }
}

// ---- convert input chunk (B,S,D) fp32 -> Abuf[(sl*64+b)][d] bf16 ----
__global__ void k_convert_x(const float* __restrict__ inp, unsigned short* __restrict__ abuf, int s0){
  int idx = blockIdx.x * 256 + threadIdx.x;
  int e = idx * 4;
  int r = e >> 10, d = e & 1023;
  int b = r & 63, sl = r >> 6;
  floatx4 v = *(const floatx4*)(inp + ((size_t)(b * 1024 + (s0 + sl)) * 1024 + d));
  unsigned long long pk = (unsigned long long)f2bf(v[0])
                        | ((unsigned long long)f2bf(v[1]) << 16)
                        | ((unsigned long long)f2bf(v[2]) << 32)
                        | ((unsigned long long)f2bf(v[3]) << 48);
  *(unsigned long long*)(abuf + (size_t)r * 1024 + d) = pk;
}

// ---- xproj GEMM: C[M][4096] = A[M][1024] @ Bt^T + (bW+bU), bf16 out ----
__global__ void __launch_bounds__(256) k_gemm_xproj(
    const unsigned short* __restrict__ A,
    const unsigned short* __restrict__ Bt,
    const float* __restrict__ bW,
    const float* __restrict__ bU,
    unsigned short* __restrict__ Cc)
{
  __shared__ unsigned short As[2][128][64];
  __shared__ unsigned short Bs[2][128][64];
  const int t = threadIdx.x;
  const int w = t >> 6;
  const int lane = t & 63;
  const int m0 = blockIdx.x * 128;
  const int n0 = blockIdx.y * 128;
  floatx4 acc[4][4];
  #pragma unroll
  for (int i = 0; i < 4; i++)
    #pragma unroll
    for (int j = 0; j < 4; j++)
      acc[i][j] = (floatx4){0.f, 0.f, 0.f, 0.f};

  auto stage = [&](int bufi, int kt){
    #pragma unroll
    for (int i = 0; i < 4; i++){
      int chunk = i * 256 + t;
      int r = chunk >> 3, j = chunk & 7;
      int js = j ^ (r & 7);
      __builtin_amdgcn_global_load_lds(
        (const __attribute__((address_space(1))) unsigned int*)(A + (size_t)(m0 + r) * 1024 + kt * 64 + js * 8),
        (__attribute__((address_space(3))) unsigned int*)(&As[bufi][0][0] + (i * 256 + w * 64) * 8), 16, 0, 0);
    }
    #pragma unroll
    for (int i = 0; i < 4; i++){
      int chunk = i * 256 + t;
      int r = chunk >> 3, j = chunk & 7;
      int js = j ^ (r & 7);
      __builtin_amdgcn_global_load_lds(
        (const __attribute__((address_space(1))) unsigned int*)(Bt + (size_t)(n0 + r) * 1024 + kt * 64 + js * 8),
        (__attribute__((address_space(3))) unsigned int*)(&Bs[bufi][0][0] + (i * 256 + w * 64) * 8), 16, 0, 0);
    }
  };

  auto compute = [&](int bufi){
    const int mi0 = (w >> 1) * 64;
    const int ni0 = (w & 1) * 64;
    #pragma unroll
    for (int kc = 0; kc < 2; kc++){
      short8 af[4], bfr[4];
      #pragma unroll
      for (int mi = 0; mi < 4; mi++){
        int row = mi0 + mi * 16 + (lane & 15);
        int j = kc * 4 + (lane >> 4);
        af[mi] = *(const short8*)&As[bufi][row][(j ^ (row & 7)) * 8];
      }
      #pragma unroll
      for (int ni = 0; ni < 4; ni++){
        int row = ni0 + ni * 16 + (lane & 15);
        int j = kc * 4 + (lane >> 4);
        bfr[ni] = *(const short8*)&Bs[bufi][row][(j ^ (row & 7)) * 8];
      }
      #pragma unroll
      for (int mi = 0; mi < 4; mi++)
        #pragma unroll
        for (int ni = 0; ni < 4; ni++)
          acc[mi][ni] = __builtin_amdgcn_mfma_f32_16x16x32_bf16(af[mi], bfr[ni], acc[mi][ni], 0, 0, 0);
    }
  };

  stage(0, 0);
  int buf = 0;
  for (int kt = 0; kt < 16; kt++){
    __syncthreads();
    if (kt < 15) stage(buf ^ 1, kt + 1);
    compute(buf);
    buf ^= 1;
  }

  {
    const int mi0 = (w >> 1) * 64;
    const int ni0 = (w & 1) * 64;
    #pragma unroll
    for (int ni = 0; ni < 4; ni++){
      int col = n0 + ni0 + ni * 16 + (lane & 15);
      float bias = bW[col] + bU[col];
      #pragma unroll
      for (int mi = 0; mi < 4; mi++){
        int mrow = m0 + mi0 + mi * 16 + (lane >> 4) * 4;
        #pragma unroll
        for (int r = 0; r < 4; r++)
          Cc[(size_t)(mrow + r) * 4096 + col] = f2bf(acc[mi][ni][r] + bias);
      }
    }
  }
}

// ---- persistent recurrent kernel: 128 WGs = 4 groups(16 batches) x 32 col-WGs ----
// Group buffer (per parity, per group): 32KB = 32 subtiles x 1KB. Subtile kc holds the
// MFMA A-frag for k in [kc*32,kc*32+32): element (r, k=kc*32+jj*8+e) at byte
// (jj*16 + r)*16 + e*2, r = batch row 0..15 (ALL REAL - no padding).
// Consumer ds_read_b128 at kc*1024 + lane*16 is exactly lane l's A-frag (R4-proven map).
// Producer: thread (b, cc2) stores its 2 cols as one 4B sc0sc1 store (R4-proven path).
__global__ void __launch_bounds__(256, 1) k_lstm_rec(
    const unsigned short* __restrict__ xp,   // [SC*64][4096] bf16
    const unsigned short* __restrict__ Ut,   // [4096][1024] bf16 (gate-major rows)
    unsigned short* hbs,                     // [2][4][32768B] h group buffers
    float* cstate,                           // [64][1024]
    float* __restrict__ out,                 // (B,S,H) fp32
    float* __restrict__ hlast,
    float* __restrict__ clast,
    int* flags,                              // 128 contiguous ints (one per WG)
    int s_base, int SC)
{
  const int t = threadIdx.x;
  const int w = t >> 6;            // wave = gate
  const int lane = t & 63;
  const int wgid = blockIdx.x;
  const int g  = wgid & 3;         // batch group: batches 16g..16g+15
  const int j  = wgid >> 2;        // col-slice: h-cols [j*32, j*32+32)
  const int B0 = g * 16;
  const int gc0 = j * 32;

  __shared__ char hsh[32 * 1024];            // 32KB staged group-h (A-frag subtiles)
  __shared__ float glds[4][16][33];          // gate exchange [gate][batch][col]

  // U in VGPRs: wave w = gate w, cols gc0..gc0+31 (two 16-col N-tiles), full K=1024.
  short8 bfrag0[32], bfrag1[32];
  {
    const unsigned short* bp0 = Ut + (size_t)(w * 1024 + gc0 + (lane & 15)) * 1024 + (lane >> 4) * 8;
    const unsigned short* bp1 = bp0 + (size_t)16 * 1024;
    #pragma unroll
    for (int kc = 0; kc < 32; kc++){
      bfrag0[kc] = *(const short8*)(bp0 + kc * 32);
      bfrag1[kc] = *(const short8*)(bp1 + kc * 32);
    }
  }

  const int b   = t >> 4;          // local batch 0..15 owned in epilogue
  const int cc2 = (t & 15) * 2;    // 2 local h-cols owned: cc2, cc2+1
  floatx2 cst;
  if (s_base == 0) cst = (floatx2){0.f, 0.f};
  else             cst = *(const floatx2*)&cstate[(size_t)(B0 + b) * 1024 + gc0 + cc2];

  int bail = 20000000;

  for (int sl = 0; sl < SC; sl++){
    const int s = s_base + sl;
    const int p = s & 1;

    // xp prefetch (independent of h) before the spin: 2 cols per gate as one 4B load
    unsigned int xu[4];
    {
      const unsigned short* xr = xp + ((size_t)(sl * 64 + B0 + b)) * 4096 + gc0 + cc2;
      #pragma unroll
      for (int gg = 0; gg < 4; gg++) xu[gg] = *(const unsigned int*)(xr + gg * 1024);
    }
    __builtin_amdgcn_sched_barrier(0);

    if (sl > 0 && w == 0){
      // GLOBAL lockstep poll: 128 WG flags, 2 coalesced loads per lane
      while (true){
        int v0 = __hip_atomic_load(&flags[lane],      __ATOMIC_RELAXED, __HIP_MEMORY_SCOPE_AGENT);
        int v1 = __hip_atomic_load(&flags[lane + 64], __ATOMIC_RELAXED, __HIP_MEMORY_SCOPE_AGENT);
        int vm = min(v0, v1);
        if (__all(vm >= s)) break;
        __builtin_amdgcn_s_sleep(1);
        if (--bail < 0) break;
      }
    }
    __syncthreads();                                    // B1
    __builtin_amdgcn_fence(__ATOMIC_ACQUIRE, "agent");  // invalidate L1/L2 (U in VGPRs)

    // stage group h (32KB) into LDS: linear global_load_lds, wave w takes subtiles [w*8, w*8+8)
    {
      const char* gsrc = (const char*)hbs + ((size_t)p * 4 + g) * 32768;
      #pragma unroll
      for (int i = 0; i < 8; i++){
        const int st = w * 8 + i;
        __builtin_amdgcn_global_load_lds(
          (const __attribute__((address_space(1))) unsigned int*)(gsrc + st * 1024 + lane * 16),
          (__attribute__((address_space(3))) unsigned int*)(hsh + st * 1024), 16, 0, 0);
      }
    }
    __syncthreads();                                    // B2 (drains vmcnt + lds)

    // GEMM: acc[ni] = h[16 x 1024] @ U_w[1024 x 32]
    floatx4 acc0 = (floatx4){0.f,0.f,0.f,0.f};
    floatx4 acc1 = (floatx4){0.f,0.f,0.f,0.f};
    const char* hp = hsh + lane * 16;
    #pragma unroll
    for (int kc = 0; kc < 32; kc++){
      short8 af = *(const short8*)(hp + kc * 1024);
      acc0 = __builtin_amdgcn_mfma_f32_16x16x32_bf16(af, bfrag0[kc], acc0, 0, 0, 0);
      acc1 = __builtin_amdgcn_mfma_f32_16x16x32_bf16(af, bfrag1[kc], acc1, 0, 0, 0);
    }

    // publish gate values (all 16 rows real). C: row=(l>>4)*4+reg, col=l&15.
    {
      const int r0 = (lane >> 4) * 4;
      const int cl = lane & 15;
      #pragma unroll
      for (int r = 0; r < 4; r++){
        glds[w][r0 + r][cl]      = acc0[r];
        glds[w][r0 + r][16 + cl] = acc1[r];
      }
    }
    __syncthreads();                                    // B3

    // epilogue: thread owns (b, cc2) and (b, cc2+1)
    float hout[2];
    #pragma unroll
    for (int d = 0; d < 2; d++){
      float fv = fsigmoid(glds[0][b][cc2 + d] + bf2f((unsigned short)(xu[0] >> (16 * d))));
      float iv = fsigmoid(glds[1][b][cc2 + d] + bf2f((unsigned short)(xu[1] >> (16 * d))));
      float ov = fsigmoid(glds[2][b][cc2 + d] + bf2f((unsigned short)(xu[2] >> (16 * d))));
      float gv = fsigmoid(glds[3][b][cc2 + d] + bf2f((unsigned short)(xu[3] >> (16 * d))));  // sigmoid, not tanh
      float cv = fv * cst[d] + iv * gv;
      cst[d] = cv;
      hout[d] = ov * ftanh(cv);
    }

    // publish h: per-thread 4B sc0sc1 store into A-frag subtile j of group buffer.
    // element (r=b, k_local=cc2): byte ((cc2>>3)*16 + b)*16 + (cc2&7)*2  (2 shorts)
    {
      unsigned int hv = (unsigned int)f2bf(hout[0]) | ((unsigned int)f2bf(hout[1]) << 16);
      void* dst = (char*)hbs + ((size_t)(p ^ 1) * 4 + g) * 32768 + j * 1024
                + (((cc2 >> 3) * 16 + b) << 4) + ((cc2 & 7) << 1);
      asm volatile("global_store_dword %0, %1, off sc0 sc1" :: "v"(dst), "v"(hv) : "memory");
    }

    if (s == 1023){
      *(floatx2*)&hlast[(size_t)(B0 + b) * 1024 + gc0 + cc2] = (floatx2){hout[0], hout[1]};
      *(floatx2*)&clast[(size_t)(B0 + b) * 1024 + gc0 + cc2] = cst;
    }

    asm volatile("s_waitcnt vmcnt(0)" ::: "memory");    // h stores acked
    __syncthreads();                                    // B4: whole WG's h published
    if (t == 0)
      __hip_atomic_store(&flags[wgid], s + 1, __ATOMIC_RELAXED, __HIP_MEMORY_SCOPE_AGENT);

    // out store off the critical path
    *(floatx2*)&out[((size_t)(B0 + b) * 1024 + s) * 1024 + gc0 + cc2] = (floatx2){hout[0], hout[1]};
  }

  *(floatx2*)&cstate[(size_t)(B0 + b) * 1024 + gc0 + cc2] = cst;
}

extern "C" void kernel_launch(void* const* d_in, const int* in_sizes, int n_in,
                              void* d_out, int out_size, void* d_ws, size_t ws_size,
                              hipStream_t stream)
{
  (void)in_sizes; (void)n_in; (void)out_size;
  const float* input_emb = (const float*)d_in[0];
  const float* W   = (const float*)d_in[1];
  const float* bWp = (const float*)d_in[2];
  const float* U   = (const float*)d_in[3];
  const float* bUp = (const float*)d_in[4];
  float* out   = (float*)d_out;
  float* hlast = out + (size_t)64 * 1024 * 1024;
  float* clast = hlast + 64 * 1024;

  char* base = (char*)d_ws;
  unsigned short* Wt  = (unsigned short*)base;  base += 8388608;   // [4096][1024] bf16
  unsigned short* Ut  = (unsigned short*)base;  base += 8388608;   // [4096][1024] bf16
  unsigned short* hbs = (unsigned short*)base;  base += 262144;    // [2][4][32KB] group h
  float* cstate       = (float*)base;           base += 262144;    // [64][1024] f32
  int* flags          = (int*)base;             base += 8192;      // 128 ints (+pad)
  size_t fixed = (size_t)(base - (char*)d_ws);
  size_t avail = ws_size > fixed ? ws_size - fixed : 0;
  int SC = 1024;
  while (SC > 8 && (size_t)SC * 655360ull > avail) SC >>= 1;
  unsigned short* Abuf = (unsigned short*)base; base += (size_t)SC * 131072;  // [SC*64][1024] bf16
  unsigned short* xpb  = (unsigned short*)base;                               // [SC*64][4096] bf16

  hipMemsetAsync(flags, 0, 8192, stream);
  hipMemsetAsync(hbs, 0, 262144, stream);       // h0 = 0 (both parities)

  k_transpose_bf16<<<dim3(16, 16, 4), 256, 0, stream>>>(W, Wt);
  k_transpose_bf16<<<dim3(16, 16, 4), 256, 0, stream>>>(U, Ut);

  int nch = 1024 / SC;
  for (int cc = 0; cc < nch; cc++){
    int s0 = cc * SC;
    k_convert_x<<<SC * 64, 256, 0, stream>>>(input_emb, Abuf, s0);
    k_gemm_xproj<<<dim3(SC / 2, 32), 256, 0, stream>>>(Abuf, Wt, bWp, bUp, xpb);
    k_lstm_rec<<<128, 256, 0, stream>>>(xpb, Ut, hbs, cstate, out, hlast, clast, flags, s0, SC);
  }
}

// Round 11
// 7764.389 us; speedup vs baseline: 1.7231x; 1.3082x over previous
//
#include <hip/hip_runtime.h>
#include <hip/hip_bf16.h>
#include <stdint.h>

// LSTM B=64 S=1024 D=1024 H=1024, gates f,i,o,g all sigmoid.
// Phase 1: xproj = x@W + bW + bU  (bf16 MFMA GEMM)
// Phase 2: persistent recurrent kernel, 128 WGs = 4 batch-groups x 32 col-WGs.
//   R11: NO global barrier, NO acquire fence, NO LDS staging. Per-group dataflow:
//   consume-all-subtiles IS the barrier (depth-2 parity proof in round notes).
//   h A-frags pulled straight to regs via agent-scope atomic loads (coherent path),
//   double-buffered 8-subtile chunks interleaved with the 64-MFMA chain.
//   Producer publish: R10's proven per-thread sc0sc1 store + vmcnt + flag.

typedef __attribute__((ext_vector_type(8))) short short8;
typedef __attribute__((ext_vector_type(4))) float floatx4;
typedef __attribute__((ext_vector_type(2))) float floatx2;

__device__ __forceinline__ unsigned short f2bf(float x){
  union { float f; unsigned int u; } v; v.f = x;
  unsigned int r = v.u + 0x7fffu + ((v.u >> 16) & 1u);
  return (unsigned short)(r >> 16);
}
__device__ __forceinline__ float bf2f(unsigned short b){
  union { unsigned int u; float f; } v; v.u = ((unsigned int)b) << 16; return v.f;
}
__device__ __forceinline__ float fsigmoid(float x){ return 1.0f / (1.0f + __expf(-x)); }
__device__ __forceinline__ float ftanh(float x){ return 1.0f - 2.0f / (1.0f + __expf(2.0f * x)); }

// ---- transpose [g][d][h] fp32 -> [g][h][d] bf16 (per-gate 1024x1024) ----
__global__ void k_transpose_bf16(const float* __restrict__ src, unsigned short* __restrict__ dst){
  __shared__ float tile[64][65];
  const int g  = blockIdx.z;
  const int d0 = blockIdx.x * 64;
  const int h0 = blockIdx.y * 64;
  const int t  = threadIdx.x;
  const float* s    = src + ((size_t)g << 20);
  unsigned short* o = dst + ((size_t)g << 20);
  #pragma unroll
  for (int i = 0; i < 16; i++){
    int e = i * 256 + t;
    int r = e >> 6, c = e & 63;
    tile[r][c] = s[(size_t)(d0 + r) * 1024 + (h0 + c)];
  }
  __syncthreads();
  #pragma unroll
  for (int i = 0; i < 16; i++){
    int e = i * 256 + t;
    int a = e >> 6, bb = e & 63;
    o[(size_t)(h0 + a) * 1024 + (d0 + bb)] = f2bf(tile[bb][a]);
  }
}

// ---- convert input chunk (B,S,D) fp32 -> Abuf[(sl*64+b)][d] bf16 ----
__global__ void k_convert_x(const float* __restrict__ inp, unsigned short* __restrict__ abuf, int s0){
  int idx = blockIdx.x * 256 + threadIdx.x;
  int e = idx * 4;
  int r = e >> 10, d = e & 1023;
  int b = r & 63, sl = r >> 6;
  floatx4 v = *(const floatx4*)(inp + ((size_t)(b * 1024 + (s0 + sl)) * 1024 + d));
  unsigned long long pk = (unsigned long long)f2bf(v[0])
                        | ((unsigned long long)f2bf(v[1]) << 16)
                        | ((unsigned long long)f2bf(v[2]) << 32)
                        | ((unsigned long long)f2bf(v[3]) << 48);
  *(unsigned long long*)(abuf + (size_t)r * 1024 + d) = pk;
}

// ---- xproj GEMM: C[M][4096] = A[M][1024] @ Bt^T + (bW+bU), bf16 out ----
__global__ void __launch_bounds__(256) k_gemm_xproj(
    const unsigned short* __restrict__ A,
    const unsigned short* __restrict__ Bt,
    const float* __restrict__ bW,
    const float* __restrict__ bU,
    unsigned short* __restrict__ Cc)
{
  __shared__ unsigned short As[2][128][64];
  __shared__ unsigned short Bs[2][128][64];
  const int t = threadIdx.x;
  const int w = t >> 6;
  const int lane = t & 63;
  const int m0 = blockIdx.x * 128;
  const int n0 = blockIdx.y * 128;
  floatx4 acc[4][4];
  #pragma unroll
  for (int i = 0; i < 4; i++)
    #pragma unroll
    for (int j = 0; j < 4; j++)
      acc[i][j] = (floatx4){0.f, 0.f, 0.f, 0.f};

  auto stage = [&](int bufi, int kt){
    #pragma unroll
    for (int i = 0; i < 4; i++){
      int chunk = i * 256 + t;
      int r = chunk >> 3, j = chunk & 7;
      int js = j ^ (r & 7);
      __builtin_amdgcn_global_load_lds(
        (const __attribute__((address_space(1))) unsigned int*)(A + (size_t)(m0 + r) * 1024 + kt * 64 + js * 8),
        (__attribute__((address_space(3))) unsigned int*)(&As[bufi][0][0] + (i * 256 + w * 64) * 8), 16, 0, 0);
    }
    #pragma unroll
    for (int i = 0; i < 4; i++){
      int chunk = i * 256 + t;
      int r = chunk >> 3, j = chunk & 7;
      int js = j ^ (r & 7);
      __builtin_amdgcn_global_load_lds(
        (const __attribute__((address_space(1))) unsigned int*)(Bt + (size_t)(n0 + r) * 1024 + kt * 64 + js * 8),
        (__attribute__((address_space(3))) unsigned int*)(&Bs[bufi][0][0] + (i * 256 + w * 64) * 8), 16, 0, 0);
    }
  };

  auto compute = [&](int bufi){
    const int mi0 = (w >> 1) * 64;
    const int ni0 = (w & 1) * 64;
    #pragma unroll
    for (int kc = 0; kc < 2; kc++){
      short8 af[4], bfr[4];
      #pragma unroll
      for (int mi = 0; mi < 4; mi++){
        int row = mi0 + mi * 16 + (lane & 15);
        int j = kc * 4 + (lane >> 4);
        af[mi] = *(const short8*)&As[bufi][row][(j ^ (row & 7)) * 8];
      }
      #pragma unroll
      for (int ni = 0; ni < 4; ni++){
        int row = ni0 + ni * 16 + (lane & 15);
        int j = kc * 4 + (lane >> 4);
        bfr[ni] = *(const short8*)&Bs[bufi][row][(j ^ (row & 7)) * 8];
      }
      #pragma unroll
      for (int mi = 0; mi < 4; mi++)
        #pragma unroll
        for (int ni = 0; ni < 4; ni++)
          acc[mi][ni] = __builtin_amdgcn_mfma_f32_16x16x32_bf16(af[mi], bfr[ni], acc[mi][ni], 0, 0, 0);
    }
  };

  stage(0, 0);
  int buf = 0;
  for (int kt = 0; kt < 16; kt++){
    __syncthreads();
    if (kt < 15) stage(buf ^ 1, kt + 1);
    compute(buf);
    buf ^= 1;
  }

  {
    const int mi0 = (w >> 1) * 64;
    const int ni0 = (w & 1) * 64;
    #pragma unroll
    for (int ni = 0; ni < 4; ni++){
      int col = n0 + ni0 + ni * 16 + (lane & 15);
      float bias = bW[col] + bU[col];
      #pragma unroll
      for (int mi = 0; mi < 4; mi++){
        int mrow = m0 + mi0 + mi * 16 + (lane >> 4) * 4;
        #pragma unroll
        for (int r = 0; r < 4; r++)
          Cc[(size_t)(mrow + r) * 4096 + col] = f2bf(acc[mi][ni][r] + bias);
      }
    }
  }
}

// ---- persistent recurrent kernel: 128 WGs = 4 groups(16 batches) x 32 col-WGs ----
// Group buffer (per parity, per group): 32KB = 32 subtiles x 1KB. Subtile kc holds the
// MFMA A-frag for k in [kc*32,kc*32+32): element (r, k=kc*32+jj*8+e) at byte
// (jj*16 + r)*16 + e*2, r = batch row 0..15. Consumer lane l reads bytes [l*16,l*16+16)
// of each subtile DIRECTLY into regs via agent-scope atomic loads (no LDS, no fence).
// Producer thread (b,cc2): one 4B sc0sc1 store (R10-proven path). flags[g*32+j] = steps
// published by WG (g,j); consume-all makes depth-2 parity safe without a barrier.
__global__ void __launch_bounds__(256, 1) k_lstm_rec(
    const unsigned short* __restrict__ xp,   // [SC*64][4096] bf16
    const unsigned short* __restrict__ Ut,   // [4096][1024] bf16 (gate-major rows)
    unsigned short* hbs,                     // [2][4][32768B] h group buffers
    float* cstate,                           // [64][1024]
    float* __restrict__ out,                 // (B,S,H) fp32
    float* __restrict__ hlast,
    float* __restrict__ clast,
    int* flags,                              // [4][32] ints (group-contiguous lines)
    int s_base, int SC)
{
  const int t = threadIdx.x;
  const int w = t >> 6;            // wave = gate
  const int lane = t & 63;
  const int wgid = blockIdx.x;
  const int g  = wgid & 3;         // batch group: batches 16g..16g+15
  const int j  = wgid >> 2;        // col-slice: h-cols [j*32, j*32+32)
  const int B0 = g * 16;
  const int gc0 = j * 32;

  __shared__ float glds[4][16][33];          // gate exchange [gate][batch][col]

  // U in VGPRs: wave w = gate w, cols gc0..gc0+31 (two 16-col N-tiles), full K=1024.
  short8 bfrag0[32], bfrag1[32];
  {
    const unsigned short* bp0 = Ut + (size_t)(w * 1024 + gc0 + (lane & 15)) * 1024 + (lane >> 4) * 8;
    const unsigned short* bp1 = bp0 + (size_t)16 * 1024;
    #pragma unroll
    for (int kc = 0; kc < 32; kc++){
      bfrag0[kc] = *(const short8*)(bp0 + kc * 32);
      bfrag1[kc] = *(const short8*)(bp1 + kc * 32);
    }
  }

  const int b   = t >> 4;          // local batch 0..15 owned in epilogue
  const int cc2 = (t & 15) * 2;    // 2 local h-cols owned: cc2, cc2+1
  floatx2 cst;
  if (s_base == 0) cst = (floatx2){0.f, 0.f};
  else             cst = *(const floatx2*)&cstate[(size_t)(B0 + b) * 1024 + gc0 + cc2];

  int bail = 20000000;
  const int fb = g * 32;

  for (int sl = 0; sl < SC; sl++){
    const int s = s_base + sl;
    const int p = s & 1;

    // xp prefetch (independent of h): 2 cols per gate as one 4B load
    unsigned int xu[4];
    {
      const unsigned short* xr = xp + ((size_t)(sl * 64 + B0 + b)) * 4096 + gc0 + cc2;
      #pragma unroll
      for (int gg = 0; gg < 4; gg++) xu[gg] = *(const unsigned int*)(xr + gg * 1024);
    }
    __builtin_amdgcn_sched_barrier(0);

    // group-scope wait: all 32 producers of THIS group published H_s
    if (s > 0 && w == 0){
      while (true){
        int v = __hip_atomic_load(&flags[fb + (lane & 31)], __ATOMIC_RELAXED, __HIP_MEMORY_SCOPE_AGENT);
        if (__all(v >= s)) break;
        __builtin_amdgcn_s_sleep(1);
        if (--bail < 0) break;
      }
    }
    __syncthreads();                                    // B1: availability known WG-wide

    const char* gsrc = (const char*)hbs + ((size_t)p * 4 + g) * 32768;
    floatx4 acc0 = (floatx4){0.f,0.f,0.f,0.f};
    floatx4 acc1 = (floatx4){0.f,0.f,0.f,0.f};

    // consume 32 subtiles straight to regs: 4 chunks of 8, double-buffered
    unsigned long long loA[8], hiA[8], loB[8], hiB[8];
    auto issue8 = [&](unsigned long long (&lo)[8], unsigned long long (&hi)[8], int ch){
      #pragma unroll
      for (int i = 0; i < 8; i++){
        const unsigned long long* sp2 = (const unsigned long long*)(gsrc + (ch * 8 + i) * 1024 + lane * 16);
        lo[i] = __hip_atomic_load(sp2,     __ATOMIC_RELAXED, __HIP_MEMORY_SCOPE_AGENT);
        hi[i] = __hip_atomic_load(sp2 + 1, __ATOMIC_RELAXED, __HIP_MEMORY_SCOPE_AGENT);
      }
    };
    auto crunch8 = [&](unsigned long long (&lo)[8], unsigned long long (&hi)[8], int ch){
      #pragma unroll
      for (int i = 0; i < 8; i++){
        union { unsigned long long q[2]; short8 v; } u;
        u.q[0] = lo[i]; u.q[1] = hi[i];
        acc0 = __builtin_amdgcn_mfma_f32_16x16x32_bf16(u.v, bfrag0[ch * 8 + i], acc0, 0, 0, 0);
        acc1 = __builtin_amdgcn_mfma_f32_16x16x32_bf16(u.v, bfrag1[ch * 8 + i], acc1, 0, 0, 0);
      }
    };
    issue8(loA, hiA, 0);
    issue8(loB, hiB, 1);
    crunch8(loA, hiA, 0);
    issue8(loA, hiA, 2);
    crunch8(loB, hiB, 1);
    issue8(loB, hiB, 3);
    crunch8(loA, hiA, 2);
    crunch8(loB, hiB, 3);

    // publish gate values (all 16 rows real). C: row=(l>>4)*4+reg, col=l&15.
    {
      const int r0 = (lane >> 4) * 4;
      const int cl = lane & 15;
      #pragma unroll
      for (int r = 0; r < 4; r++){
        glds[w][r0 + r][cl]      = acc0[r];
        glds[w][r0 + r][16 + cl] = acc1[r];
      }
    }
    __syncthreads();                                    // B3

    // epilogue: thread owns (b, cc2) and (b, cc2+1)
    float hout[2];
    #pragma unroll
    for (int d = 0; d < 2; d++){
      float fv = fsigmoid(glds[0][b][cc2 + d] + bf2f((unsigned short)(xu[0] >> (16 * d))));
      float iv = fsigmoid(glds[1][b][cc2 + d] + bf2f((unsigned short)(xu[1] >> (16 * d))));
      float ov = fsigmoid(glds[2][b][cc2 + d] + bf2f((unsigned short)(xu[2] >> (16 * d))));
      float gv = fsigmoid(glds[3][b][cc2 + d] + bf2f((unsigned short)(xu[3] >> (16 * d))));  // sigmoid, not tanh
      float cv = fv * cst[d] + iv * gv;
      cst[d] = cv;
      hout[d] = ov * ftanh(cv);
    }

    // publish h: per-thread 4B sc0sc1 store into A-frag subtile j of group buffer.
    {
      unsigned int hv = (unsigned int)f2bf(hout[0]) | ((unsigned int)f2bf(hout[1]) << 16);
      void* dst = (char*)hbs + ((size_t)(p ^ 1) * 4 + g) * 32768 + j * 1024
                + (((cc2 >> 3) * 16 + b) << 4) + ((cc2 & 7) << 1);
      asm volatile("global_store_dword %0, %1, off sc0 sc1" :: "v"(dst), "v"(hv) : "memory");
    }

    if (s == 1023){
      *(floatx2*)&hlast[(size_t)(B0 + b) * 1024 + gc0 + cc2] = (floatx2){hout[0], hout[1]};
      *(floatx2*)&clast[(size_t)(B0 + b) * 1024 + gc0 + cc2] = cst;
    }

    asm volatile("s_waitcnt vmcnt(0)" ::: "memory");    // own wave's h stores acked
    __syncthreads();                                    // B4: all waves drained
    if (t == 0)
      __hip_atomic_store(&flags[fb + j], s + 1, __ATOMIC_RELAXED, __HIP_MEMORY_SCOPE_AGENT);

    // out store off the critical path
    *(floatx2*)&out[((size_t)(B0 + b) * 1024 + s) * 1024 + gc0 + cc2] = (floatx2){hout[0], hout[1]};
  }

  *(floatx2*)&cstate[(size_t)(B0 + b) * 1024 + gc0 + cc2] = cst;
}

extern "C" void kernel_launch(void* const* d_in, const int* in_sizes, int n_in,
                              void* d_out, int out_size, void* d_ws, size_t ws_size,
                              hipStream_t stream)
{
  (void)in_sizes; (void)n_in; (void)out_size;
  const float* input_emb = (const float*)d_in[0];
  const float* W   = (const float*)d_in[1];
  const float* bWp = (const float*)d_in[2];
  const float* U   = (const float*)d_in[3];
  const float* bUp = (const float*)d_in[4];
  float* out   = (float*)d_out;
  float* hlast = out + (size_t)64 * 1024 * 1024;
  float* clast = hlast + 64 * 1024;

  char* base = (char*)d_ws;
  unsigned short* Wt  = (unsigned short*)base;  base += 8388608;   // [4096][1024] bf16
  unsigned short* Ut  = (unsigned short*)base;  base += 8388608;   // [4096][1024] bf16
  unsigned short* hbs = (unsigned short*)base;  base += 262144;    // [2][4][32KB] group h
  float* cstate       = (float*)base;           base += 262144;    // [64][1024] f32
  int* flags          = (int*)base;             base += 8192;      // [4][32] ints (+pad)
  size_t fixed = (size_t)(base - (char*)d_ws);
  size_t avail = ws_size > fixed ? ws_size - fixed : 0;
  int SC = 1024;
  while (SC > 8 && (size_t)SC * 655360ull > avail) SC >>= 1;
  unsigned short* Abuf = (unsigned short*)base; base += (size_t)SC * 131072;  // [SC*64][1024] bf16
  unsigned short* xpb  = (unsigned short*)base;                               // [SC*64][4096] bf16

  hipMemsetAsync(flags, 0, 8192, stream);
  hipMemsetAsync(hbs, 0, 262144, stream);       // h0 = 0 (both parities)

  k_transpose_bf16<<<dim3(16, 16, 4), 256, 0, stream>>>(W, Wt);
  k_transpose_bf16<<<dim3(16, 16, 4), 256, 0, stream>>>(U, Ut);

  int nch = 1024 / SC;
  for (int cc = 0; cc < nch; cc++){
    int s0 = cc * SC;
    k_convert_x<<<SC * 64, 256, 0, stream>>>(input_emb, Abuf, s0);
    k_gemm_xproj<<<dim3(SC / 2, 32), 256, 0, stream>>>(Abuf, Wt, bWp, bUp, xpb);
    k_lstm_rec<<<128, 256, 0, stream>>>(xpb, Ut, hbs, cstate, out, hlast, clast, flags, s0, SC);
  }
}

// Round 12
// 6318.988 us; speedup vs baseline: 2.1173x; 1.2287x over previous
//
#include <hip/hip_runtime.h>
#include <hip/hip_bf16.h>
#include <stdint.h>

// LSTM B=64 S=1024 D=1024 H=1024, gates f,i,o,g all sigmoid.
// Phase 1: xproj = x@W + bW + bU  (bf16 MFMA GEMM)
// Phase 2: persistent recurrent kernel, 128 WGs = 4 batch-groups x 32 col-WGs.
//   R12: R11 + (1) publish via AGENT-scope atomic stores (L3-resident; the old
//   sc0sc1 asm was SYSTEM scope -> h round-tripped through HBM, seen in
//   FETCH/WRITE counters), (2) per-wave per-chunk flag polling (B1 removed;
//   straggler wait overlaps loads+MFMA of earlier chunks).

typedef __attribute__((ext_vector_type(8))) short short8;
typedef __attribute__((ext_vector_type(4))) float floatx4;
typedef __attribute__((ext_vector_type(2))) float floatx2;

__device__ __forceinline__ unsigned short f2bf(float x){
  union { float f; unsigned int u; } v; v.f = x;
  unsigned int r = v.u + 0x7fffu + ((v.u >> 16) & 1u);
  return (unsigned short)(r >> 16);
}
__device__ __forceinline__ float bf2f(unsigned short b){
  union { unsigned int u; float f; } v; v.u = ((unsigned int)b) << 16; return v.f;
}
__device__ __forceinline__ float fsigmoid(float x){ return 1.0f / (1.0f + __expf(-x)); }
__device__ __forceinline__ float ftanh(float x){ return 1.0f - 2.0f / (1.0f + __expf(2.0f * x)); }

// ---- transpose [g][d][h] fp32 -> [g][h][d] bf16 (per-gate 1024x1024) ----
__global__ void k_transpose_bf16(const float* __restrict__ src, unsigned short* __restrict__ dst){
  __shared__ float tile[64][65];
  const int g  = blockIdx.z;
  const int d0 = blockIdx.x * 64;
  const int h0 = blockIdx.y * 64;
  const int t  = threadIdx.x;
  const float* s    = src + ((size_t)g << 20);
  unsigned short* o = dst + ((size_t)g << 20);
  #pragma unroll
  for (int i = 0; i < 16; i++){
    int e = i * 256 + t;
    int r = e >> 6, c = e & 63;
    tile[r][c] = s[(size_t)(d0 + r) * 1024 + (h0 + c)];
  }
  __syncthreads();
  #pragma unroll
  for (int i = 0; i < 16; i++){
    int e = i * 256 + t;
    int a = e >> 6, bb = e & 63;
    o[(size_t)(h0 + a) * 1024 + (d0 + bb)] = f2bf(tile[bb][a]);
  }
}

// ---- convert input chunk (B,S,D) fp32 -> Abuf[(sl*64+b)][d] bf16 ----
__global__ void k_convert_x(const float* __restrict__ inp, unsigned short* __restrict__ abuf, int s0){
  int idx = blockIdx.x * 256 + threadIdx.x;
  int e = idx * 4;
  int r = e >> 10, d = e & 1023;
  int b = r & 63, sl = r >> 6;
  floatx4 v = *(const floatx4*)(inp + ((size_t)(b * 1024 + (s0 + sl)) * 1024 + d));
  unsigned long long pk = (unsigned long long)f2bf(v[0])
                        | ((unsigned long long)f2bf(v[1]) << 16)
                        | ((unsigned long long)f2bf(v[2]) << 32)
                        | ((unsigned long long)f2bf(v[3]) << 48);
  *(unsigned long long*)(abuf + (size_t)r * 1024 + d) = pk;
}

// ---- xproj GEMM: C[M][4096] = A[M][1024] @ Bt^T + (bW+bU), bf16 out ----
__global__ void __launch_bounds__(256) k_gemm_xproj(
    const unsigned short* __restrict__ A,
    const unsigned short* __restrict__ Bt,
    const float* __restrict__ bW,
    const float* __restrict__ bU,
    unsigned short* __restrict__ Cc)
{
  __shared__ unsigned short As[2][128][64];
  __shared__ unsigned short Bs[2][128][64];
  const int t = threadIdx.x;
  const int w = t >> 6;
  const int lane = t & 63;
  const int m0 = blockIdx.x * 128;
  const int n0 = blockIdx.y * 128;
  floatx4 acc[4][4];
  #pragma unroll
  for (int i = 0; i < 4; i++)
    #pragma unroll
    for (int j = 0; j < 4; j++)
      acc[i][j] = (floatx4){0.f, 0.f, 0.f, 0.f};

  auto stage = [&](int bufi, int kt){
    #pragma unroll
    for (int i = 0; i < 4; i++){
      int chunk = i * 256 + t;
      int r = chunk >> 3, j = chunk & 7;
      int js = j ^ (r & 7);
      __builtin_amdgcn_global_load_lds(
        (const __attribute__((address_space(1))) unsigned int*)(A + (size_t)(m0 + r) * 1024 + kt * 64 + js * 8),
        (__attribute__((address_space(3))) unsigned int*)(&As[bufi][0][0] + (i * 256 + w * 64) * 8), 16, 0, 0);
    }
    #pragma unroll
    for (int i = 0; i < 4; i++){
      int chunk = i * 256 + t;
      int r = chunk >> 3, j = chunk & 7;
      int js = j ^ (r & 7);
      __builtin_amdgcn_global_load_lds(
        (const __attribute__((address_space(1))) unsigned int*)(Bt + (size_t)(n0 + r) * 1024 + kt * 64 + js * 8),
        (__attribute__((address_space(3))) unsigned int*)(&Bs[bufi][0][0] + (i * 256 + w * 64) * 8), 16, 0, 0);
    }
  };

  auto compute = [&](int bufi){
    const int mi0 = (w >> 1) * 64;
    const int ni0 = (w & 1) * 64;
    #pragma unroll
    for (int kc = 0; kc < 2; kc++){
      short8 af[4], bfr[4];
      #pragma unroll
      for (int mi = 0; mi < 4; mi++){
        int row = mi0 + mi * 16 + (lane & 15);
        int j = kc * 4 + (lane >> 4);
        af[mi] = *(const short8*)&As[bufi][row][(j ^ (row & 7)) * 8];
      }
      #pragma unroll
      for (int ni = 0; ni < 4; ni++){
        int row = ni0 + ni * 16 + (lane & 15);
        int j = kc * 4 + (lane >> 4);
        bfr[ni] = *(const short8*)&Bs[bufi][row][(j ^ (row & 7)) * 8];
      }
      #pragma unroll
      for (int mi = 0; mi < 4; mi++)
        #pragma unroll
        for (int ni = 0; ni < 4; ni++)
          acc[mi][ni] = __builtin_amdgcn_mfma_f32_16x16x32_bf16(af[mi], bfr[ni], acc[mi][ni], 0, 0, 0);
    }
  };

  stage(0, 0);
  int buf = 0;
  for (int kt = 0; kt < 16; kt++){
    __syncthreads();
    if (kt < 15) stage(buf ^ 1, kt + 1);
    compute(buf);
    buf ^= 1;
  }

  {
    const int mi0 = (w >> 1) * 64;
    const int ni0 = (w & 1) * 64;
    #pragma unroll
    for (int ni = 0; ni < 4; ni++){
      int col = n0 + ni0 + ni * 16 + (lane & 15);
      float bias = bW[col] + bU[col];
      #pragma unroll
      for (int mi = 0; mi < 4; mi++){
        int mrow = m0 + mi0 + mi * 16 + (lane >> 4) * 4;
        #pragma unroll
        for (int r = 0; r < 4; r++)
          Cc[(size_t)(mrow + r) * 4096 + col] = f2bf(acc[mi][ni][r] + bias);
      }
    }
  }
}

// ---- persistent recurrent kernel: 128 WGs = 4 groups(16 batches) x 32 col-WGs ----
// Group buffer (per parity, per group): 32KB = 32 subtiles x 1KB. Subtile kc holds the
// MFMA A-frag for k in [kc*32,kc*32+32): element (r, k=kc*32+jj*8+e) at byte
// (jj*16 + r)*16 + e*2, r = batch row 0..15. Consumer lane l reads bytes [l*16,l*16+16)
// of each subtile straight into regs via AGENT-scope atomic loads (L3-coherent).
// Producer thread (b,cc2): one 4B AGENT-scope atomic store (L3-resident, not HBM).
// flags[g*32+j] = steps published by WG (g,j); consume-all makes depth-2 parity safe.
__global__ void __launch_bounds__(256, 1) k_lstm_rec(
    const unsigned short* __restrict__ xp,   // [SC*64][4096] bf16
    const unsigned short* __restrict__ Ut,   // [4096][1024] bf16 (gate-major rows)
    unsigned short* hbs,                     // [2][4][32768B] h group buffers
    float* cstate,                           // [64][1024]
    float* __restrict__ out,                 // (B,S,H) fp32
    float* __restrict__ hlast,
    float* __restrict__ clast,
    int* flags,                              // [4][32] ints (group-contiguous lines)
    int s_base, int SC)
{
  const int t = threadIdx.x;
  const int w = t >> 6;            // wave = gate
  const int lane = t & 63;
  const int wgid = blockIdx.x;
  const int g  = wgid & 3;         // batch group: batches 16g..16g+15
  const int j  = wgid >> 2;        // col-slice: h-cols [j*32, j*32+32)
  const int B0 = g * 16;
  const int gc0 = j * 32;

  __shared__ float glds[4][16][33];          // gate exchange [gate][batch][col]

  // U in VGPRs: wave w = gate w, cols gc0..gc0+31 (two 16-col N-tiles), full K=1024.
  short8 bfrag0[32], bfrag1[32];
  {
    const unsigned short* bp0 = Ut + (size_t)(w * 1024 + gc0 + (lane & 15)) * 1024 + (lane >> 4) * 8;
    const unsigned short* bp1 = bp0 + (size_t)16 * 1024;
    #pragma unroll
    for (int kc = 0; kc < 32; kc++){
      bfrag0[kc] = *(const short8*)(bp0 + kc * 32);
      bfrag1[kc] = *(const short8*)(bp1 + kc * 32);
    }
  }

  const int b   = t >> 4;          // local batch 0..15 owned in epilogue
  const int cc2 = (t & 15) * 2;    // 2 local h-cols owned: cc2, cc2+1
  floatx2 cst;
  if (s_base == 0) cst = (floatx2){0.f, 0.f};
  else             cst = *(const floatx2*)&cstate[(size_t)(B0 + b) * 1024 + gc0 + cc2];

  int bail = 20000000;
  const int fb = g * 32;

  for (int sl = 0; sl < SC; sl++){
    const int s = s_base + sl;
    const int p = s & 1;

    // xp prefetch (independent of h): 2 cols per gate as one 4B load
    unsigned int xu[4];
    {
      const unsigned short* xr = xp + ((size_t)(sl * 64 + B0 + b)) * 4096 + gc0 + cc2;
      #pragma unroll
      for (int gg = 0; gg < 4; gg++) xu[gg] = *(const unsigned int*)(xr + gg * 1024);
    }
    __builtin_amdgcn_sched_barrier(0);

    const char* gsrc = (const char*)hbs + ((size_t)p * 4 + g) * 32768;
    floatx4 acc0 = (floatx4){0.f,0.f,0.f,0.f};
    floatx4 acc1 = (floatx4){0.f,0.f,0.f,0.f};

    // per-wave per-chunk wait: only the 8 producers of chunk c gate chunk c's loads
    auto wait_chunk = [&](int c){
      if (s == 0) return;
      const int* fp2 = &flags[fb + c * 8 + (lane & 7)];
      while (true){
        int v = __hip_atomic_load(fp2, __ATOMIC_RELAXED, __HIP_MEMORY_SCOPE_AGENT);
        if (__all(v >= s)) break;
        __builtin_amdgcn_s_sleep(1);
        if (--bail < 0) break;
      }
    };

    unsigned long long loA[8], hiA[8], loB[8], hiB[8];
    auto issue8 = [&](unsigned long long (&lo)[8], unsigned long long (&hi)[8], int ch){
      #pragma unroll
      for (int i = 0; i < 8; i++){
        const unsigned long long* sp2 = (const unsigned long long*)(gsrc + (ch * 8 + i) * 1024 + lane * 16);
        lo[i] = __hip_atomic_load(sp2,     __ATOMIC_RELAXED, __HIP_MEMORY_SCOPE_AGENT);
        hi[i] = __hip_atomic_load(sp2 + 1, __ATOMIC_RELAXED, __HIP_MEMORY_SCOPE_AGENT);
      }
    };
    auto crunch8 = [&](unsigned long long (&lo)[8], unsigned long long (&hi)[8], int ch){
      #pragma unroll
      for (int i = 0; i < 8; i++){
        union { unsigned long long q[2]; short8 v; } u;
        u.q[0] = lo[i]; u.q[1] = hi[i];
        acc0 = __builtin_amdgcn_mfma_f32_16x16x32_bf16(u.v, bfrag0[ch * 8 + i], acc0, 0, 0, 0);
        acc1 = __builtin_amdgcn_mfma_f32_16x16x32_bf16(u.v, bfrag1[ch * 8 + i], acc1, 0, 0, 0);
      }
    };
    wait_chunk(0);
    issue8(loA, hiA, 0);
    wait_chunk(1);
    issue8(loB, hiB, 1);
    crunch8(loA, hiA, 0);
    wait_chunk(2);
    issue8(loA, hiA, 2);
    crunch8(loB, hiB, 1);
    wait_chunk(3);
    issue8(loB, hiB, 3);
    crunch8(loA, hiA, 2);
    crunch8(loB, hiB, 3);

    // publish gate values (all 16 rows real). C: row=(l>>4)*4+reg, col=l&15.
    {
      const int r0 = (lane >> 4) * 4;
      const int cl = lane & 15;
      #pragma unroll
      for (int r = 0; r < 4; r++){
        glds[w][r0 + r][cl]      = acc0[r];
        glds[w][r0 + r][16 + cl] = acc1[r];
      }
    }
    __syncthreads();                                    // B3

    // epilogue: thread owns (b, cc2) and (b, cc2+1)
    float hout[2];
    #pragma unroll
    for (int d = 0; d < 2; d++){
      float fv = fsigmoid(glds[0][b][cc2 + d] + bf2f((unsigned short)(xu[0] >> (16 * d))));
      float iv = fsigmoid(glds[1][b][cc2 + d] + bf2f((unsigned short)(xu[1] >> (16 * d))));
      float ov = fsigmoid(glds[2][b][cc2 + d] + bf2f((unsigned short)(xu[2] >> (16 * d))));
      float gv = fsigmoid(glds[3][b][cc2 + d] + bf2f((unsigned short)(xu[3] >> (16 * d))));  // sigmoid, not tanh
      float cv = fv * cst[d] + iv * gv;
      cst[d] = cv;
      hout[d] = ov * ftanh(cv);
    }

    // publish h: per-thread 4B AGENT-scope atomic store (L3-resident) into subtile j.
    {
      unsigned int hv = (unsigned int)f2bf(hout[0]) | ((unsigned int)f2bf(hout[1]) << 16);
      unsigned int* dst = (unsigned int*)((char*)hbs + ((size_t)(p ^ 1) * 4 + g) * 32768 + j * 1024
                + (((cc2 >> 3) * 16 + b) << 4) + ((cc2 & 7) << 1));
      __hip_atomic_store(dst, hv, __ATOMIC_RELAXED, __HIP_MEMORY_SCOPE_AGENT);
    }

    if (s == 1023){
      *(floatx2*)&hlast[(size_t)(B0 + b) * 1024 + gc0 + cc2] = (floatx2){hout[0], hout[1]};
      *(floatx2*)&clast[(size_t)(B0 + b) * 1024 + gc0 + cc2] = cst;
    }

    asm volatile("s_waitcnt vmcnt(0)" ::: "memory");    // own wave's h stores acked at L3
    __syncthreads();                                    // B4: all waves drained
    if (t == 0)
      __hip_atomic_store(&flags[fb + j], s + 1, __ATOMIC_RELAXED, __HIP_MEMORY_SCOPE_AGENT);

    // out store off the critical path
    *(floatx2*)&out[((size_t)(B0 + b) * 1024 + s) * 1024 + gc0 + cc2] = (floatx2){hout[0], hout[1]};
  }

  *(floatx2*)&cstate[(size_t)(B0 + b) * 1024 + gc0 + cc2] = cst;
}

extern "C" void kernel_launch(void* const* d_in, const int* in_sizes, int n_in,
                              void* d_out, int out_size, void* d_ws, size_t ws_size,
                              hipStream_t stream)
{
  (void)in_sizes; (void)n_in; (void)out_size;
  const float* input_emb = (const float*)d_in[0];
  const float* W   = (const float*)d_in[1];
  const float* bWp = (const float*)d_in[2];
  const float* U   = (const float*)d_in[3];
  const float* bUp = (const float*)d_in[4];
  float* out   = (float*)d_out;
  float* hlast = out + (size_t)64 * 1024 * 1024;
  float* clast = hlast + 64 * 1024;

  char* base = (char*)d_ws;
  unsigned short* Wt  = (unsigned short*)base;  base += 8388608;   // [4096][1024] bf16
  unsigned short* Ut  = (unsigned short*)base;  base += 8388608;   // [4096][1024] bf16
  unsigned short* hbs = (unsigned short*)base;  base += 262144;    // [2][4][32KB] group h
  float* cstate       = (float*)base;           base += 262144;    // [64][1024] f32
  int* flags          = (int*)base;             base += 8192;      // [4][32] ints (+pad)
  size_t fixed = (size_t)(base - (char*)d_ws);
  size_t avail = ws_size > fixed ? ws_size - fixed : 0;
  int SC = 1024;
  while (SC > 8 && (size_t)SC * 655360ull > avail) SC >>= 1;
  unsigned short* Abuf = (unsigned short*)base; base += (size_t)SC * 131072;  // [SC*64][1024] bf16
  unsigned short* xpb  = (unsigned short*)base;                               // [SC*64][4096] bf16

  hipMemsetAsync(flags, 0, 8192, stream);
  hipMemsetAsync(hbs, 0, 262144, stream);       // h0 = 0 (both parities)

  k_transpose_bf16<<<dim3(16, 16, 4), 256, 0, stream>>>(W, Wt);
  k_transpose_bf16<<<dim3(16, 16, 4), 256, 0, stream>>>(U, Ut);

  int nch = 1024 / SC;
  for (int cc = 0; cc < nch; cc++){
    int s0 = cc * SC;
    k_convert_x<<<SC * 64, 256, 0, stream>>>(input_emb, Abuf, s0);
    k_gemm_xproj<<<dim3(SC / 2, 32), 256, 0, stream>>>(Abuf, Wt, bWp, bUp, xpb);
    k_lstm_rec<<<128, 256, 0, stream>>>(xpb, Ut, hbs, cstate, out, hlast, clast, flags, s0, SC);
  }
}